// Round 2
// baseline (3419.304 us; speedup 1.0000x reference)
//
#include <hip/hip_runtime.h>
#include <math.h>

#define TB 256

static __device__ __forceinline__ int gtid() { return blockIdx.x * blockDim.x + threadIdx.x; }

__global__ void fill_kernel(float* __restrict__ p, int n, float v) {
  int i = gtid(); if (i < n) p[i] = v;
}

__global__ void zero_int_kernel(int* __restrict__ p, int n) {
  int i = gtid(); if (i < n) p[i] = 0;
}

__global__ void count_kernel(const int* __restrict__ rows, int e, int* __restrict__ deg) {
  int i = gtid(); if (i < e) atomicAdd(&deg[rows[i]], 1);
}

__global__ void dinv_kernel(const int* __restrict__ deg, float* __restrict__ dinv, int n) {
  int i = gtid(); if (i < n) { int d = deg[i]; dinv[i] = (d > 0) ? rsqrtf((float)d) : 0.0f; }
}

// single-block exclusive scan; also writes out[n] = total
__global__ void exscan_kernel(const int* __restrict__ in, int* __restrict__ out, int n) {
  __shared__ int tile[1024];
  __shared__ int carry_s;
  if (threadIdx.x == 0) carry_s = 0;
  __syncthreads();
  for (int base = 0; base < n; base += 1024) {
    int i = base + (int)threadIdx.x;
    int v = (i < n) ? in[i] : 0;
    tile[threadIdx.x] = v;
    __syncthreads();
    for (int o = 1; o < 1024; o <<= 1) {
      int t = (threadIdx.x >= (unsigned)o) ? tile[threadIdx.x - o] : 0;
      __syncthreads();
      tile[threadIdx.x] += t;
      __syncthreads();
    }
    if (i < n) out[i] = carry_s + tile[threadIdx.x] - v;
    __syncthreads();
    if (threadIdx.x == 1023) carry_s += tile[1023];
    __syncthreads();
  }
  if (threadIdx.x == 0) out[n] = carry_s;
}

__global__ void fill_edge_kernel(const int* __restrict__ rows, const int* __restrict__ cols, int e,
                                 const int* __restrict__ offs, int* __restrict__ cursor,
                                 const float* __restrict__ dinv,
                                 int* __restrict__ ccol, float* __restrict__ cw) {
  int i = gtid(); if (i >= e) return;
  int r = rows[i], c = cols[i];
  int p = atomicAdd(&cursor[r], 1);
  int idx = offs[r] + p;
  ccol[idx] = c;
  cw[idx] = dinv[r] * dinv[c];
}

__global__ void fill_pool_kernel(const int* __restrict__ rows, const int* __restrict__ cols,
                                 const float* __restrict__ vals, int e,
                                 const int* __restrict__ offs, int* __restrict__ cursor,
                                 int* __restrict__ ccol, float* __restrict__ cw) {
  int i = gtid(); if (i >= e) return;
  int r = rows[i];
  int p = atomicAdd(&cursor[r], 1);
  int idx = offs[r] + p;
  ccol[idx] = cols[i];
  cw[idx] = vals[i];
}

// Per-plane gather over group-planar features. Plane row = 128 floats = 32 float4.
// blockIdx.y selects the plane (xPl4 / oPl4 are plane strides in float4 units;
// pass 0 when gridDim.y==1 and pointers pre-offset).
// MODE 0: out = sum ; MODE 1: out = 2*sum - sub (sub stride == out stride; in-place OK)
template<int MODE>
__global__ void gather_kernel(const float4* __restrict__ x, const int* __restrict__ offs,
                              const int* __restrict__ ccol, const float* __restrict__ cw,
                              const float4* __restrict__ sub, float4* __restrict__ out,
                              int n, int xPl4, int oPl4) {
  int t = blockIdx.x * blockDim.x + threadIdx.x;
  if (t >= n * 32) return;
  long long gx = (long long)blockIdx.y * xPl4;
  long long go = (long long)blockIdx.y * oPl4;
  int v = t >> 5, j = t & 31;
  int s = offs[v], en = offs[v + 1];
  float ax = 0.f, ay = 0.f, az = 0.f, aw = 0.f;
  for (int i = s; i < en; ++i) {
    float w = cw[i];
    float4 xv = x[gx + (long long)ccol[i] * 32 + j];
    ax += w * xv.x; ay += w * xv.y; az += w * xv.z; aw += w * xv.w;
  }
  if (MODE == 1) {
    float4 sv = sub[go + t];
    ax = 2.f * ax - sv.x; ay = 2.f * ay - sv.y; az = 2.f * az - sv.z; aw = 2.f * aw - sv.w;
  }
  float4 o; o.x = ax; o.y = ay; o.z = az; o.w = aw;
  out[go + t] = o;
}

// out[god][v][b][d8] (init ? bias : +=) sum_{c in GIN*8} tx[gi][v][b][c8] * Wk[c][d]
// tx points at first input plane; Wk points at W[k] row g0*8 (GIN*8 x COUT contiguous).
template<int GIN, int COUT>
__global__ void gemm_kernel(const float* __restrict__ tx, long long txPl,
                            const float* __restrict__ Wk, const float* __restrict__ bias,
                            float* __restrict__ out, long long outPl, int n, int initf) {
  __shared__ float sW[GIN * 8 * COUT];
  for (int i = threadIdx.x; i < GIN * 8 * COUT; i += blockDim.x) sW[i] = Wk[i];
  __syncthreads();
  int t = gtid();
  if (t >= n * 16) return;
  long long rowoff = (long long)(t >> 4) * 128 + (long long)(t & 15) * 8;
  float a[GIN * 8];
  #pragma unroll
  for (int gi = 0; gi < GIN; ++gi)
    #pragma unroll
    for (int c = 0; c < 8; ++c)
      a[gi * 8 + c] = tx[gi * txPl + rowoff + c];
  #pragma unroll
  for (int gd = 0; gd < COUT / 8; ++gd) {
    long long oa = (long long)gd * outPl + rowoff;
    float o[8];
    if (initf) {
      #pragma unroll
      for (int d = 0; d < 8; ++d) o[d] = bias[gd * 8 + d];
    } else {
      #pragma unroll
      for (int d = 0; d < 8; ++d) o[d] = out[oa + d];
    }
    #pragma unroll
    for (int c = 0; c < GIN * 8; ++c) {
      float av = a[c];
      #pragma unroll
      for (int d = 0; d < 8; ++d) o[d] += av * sW[c * COUT + gd * 8 + d];
    }
    #pragma unroll
    for (int d = 0; d < 8; ++d) out[oa + d] = o[d];
  }
}

// final Cheb GEMM slice: tx is one level-0 plane [v][b][8]; out layout [b][n][3] (d_out)
__global__ void gemm_out_kernel(const float* __restrict__ tx, const float* __restrict__ Wk,
                                const float* __restrict__ bias, float* __restrict__ out,
                                int n, int initf) {
  int t = gtid();
  if (t >= n * 16) return;
  int b = t / n;
  int v = t - b * n;
  const float* a = tx + (long long)v * 128 + (long long)b * 8;
  long long ob = (long long)t * 3;
  float acc0, acc1, acc2;
  if (initf) { acc0 = bias[0]; acc1 = bias[1]; acc2 = bias[2]; }
  else { acc0 = out[ob]; acc1 = out[ob + 1]; acc2 = out[ob + 2]; }
  #pragma unroll
  for (int c = 0; c < 8; ++c) {
    float av = a[c];
    acc0 += av * Wk[c * 3 + 0];
    acc1 += av * Wk[c * 3 + 1];
    acc2 += av * Wk[c * 3 + 2];
  }
  out[ob] = acc0; out[ob + 1] = acc1; out[ob + 2] = acc2;
}

__global__ void elu_kernel(const float* __restrict__ src, float* __restrict__ dst, int n) {
  int i = gtid(); if (i < n) { float v = src[i]; dst[i] = (v > 0.f) ? v : expm1f(v); }
}

// h group-planar: out[g][v][b][c8], c = g*8+c8, v<157, b<16
__global__ void linear_kernel(const float* __restrict__ x, const float* __restrict__ w,
                              const float* __restrict__ bias, float* __restrict__ out) {
  int t = gtid();
  const int TOT = 157 * 16 * 64;
  if (t >= TOT) return;
  int c8 = t & 7;
  int b = (t >> 3) & 15;
  int vg = t >> 7;
  int v = vg % 157;
  int g = vg / 157;
  int colw = v * 64 + g * 8 + c8;
  float acc = bias[colw];
  const float* xr = x + b * 128;
  for (int k = 0; k < 128; ++k) acc += xr[k] * w[k * 10048 + colw];
  out[t] = acc;
}

extern "C" void kernel_launch(void* const* d_in, const int* in_sizes, int n_in,
                              void* d_out, int out_size, void* d_ws, size_t ws_size,
                              hipStream_t stream) {
  const int N[5] = {40000, 10000, 2500, 625, 157};
  const int E[4] = {240000, 60000, 15000, 3750};
  const int NNZ[4] = {120000, 30000, 7500, 1875};

  const float* x     = (const float*)d_in[0];
  const float* lin_w = (const float*)d_in[1];
  const float* lin_b = (const float*)d_in[2];
  const int* edge[4] = {(const int*)d_in[3], (const int*)d_in[4], (const int*)d_in[5], (const int*)d_in[6]};
  const int* up_row[4]; const int* up_col[4]; const float* up_val[4];
  for (int i = 0; i < 4; ++i) {
    up_row[i] = (const int*)d_in[7 + 3 * i];
    up_col[i] = (const int*)d_in[8 + 3 * i];
    up_val[i] = (const float*)d_in[9 + 3 * i];
  }
  const float* W_[5] = {(const float*)d_in[19], (const float*)d_in[21], (const float*)d_in[23],
                        (const float*)d_in[25], (const float*)d_in[27]};
  const float* b_[5] = {(const float*)d_in[20], (const float*)d_in[22], (const float*)d_in[24],
                        (const float*)d_in[26], (const float*)d_in[28]};

  char* ws = (char*)d_ws;
  size_t off = 0;
  auto alloc = [&](size_t bytes) -> void* {
    void* p = ws + off;
    off = (off + bytes + 255) & ~(size_t)255;
    return p;
  };
  auto cdiv = [](int a, int b) { return (a + b - 1) / b; };

  float* O = (float*)alloc(20480000ull * 4);  // 81.92 MB: out accumulator / final h0
  float* H = (float*)alloc(5120000ull * 4);   // 20.48 MB: inter-level h carrier
  float* X = (float*)alloc(5120000ull * 4);   // 20.48 MB: tx scratch
  float* Y = (float*)alloc(5120000ull * 4);   // 20.48 MB: tx scratch
  int*   deg    = (int*)alloc(40000 * 4);
  int*   cursor = (int*)alloc(40000 * 4);
  int*   offs_p = (int*)alloc(40001 * 4);
  int*   offs_e = (int*)alloc(40001 * 4);
  float* dinv   = (float*)alloc(40000 * 4);
  int*   pcol   = (int*)alloc(120000 * 4);
  float* pw     = (float*)alloc(120000 * 4);
  int*   ecol   = (int*)alloc(240000 * 4);
  float* ew     = (float*)alloc(240000 * 4);

  if (off > ws_size) {
    // diagnostic sentinel: encode ws_size (MB) into the output
    fill_kernel<<<cdiv(out_size, TB), TB, 0, stream>>>((float*)d_out, out_size,
                                                       (float)(ws_size >> 20));
    return;
  }

  linear_kernel<<<cdiv(157 * 16 * 64, TB), TB, 0, stream>>>(x, lin_w, lin_b, H);

  const int CIN[4] = {64, 64, 32, 32};
  const int COUTA[4] = {64, 32, 32, 32};

  for (int j = 0; j < 4; ++j) {
    int lvl = 3 - j;
    int n = N[lvl], e = E[lvl], nnz = NNZ[lvl], np = N[lvl + 1];
    int cin = CIN[j], cout = COUTA[j];
    int Gin = cin / 8;

    // ---- pool CSR ----
    zero_int_kernel<<<cdiv(n, TB), TB, 0, stream>>>(deg, n);
    count_kernel<<<cdiv(nnz, TB), TB, 0, stream>>>(up_row[lvl], nnz, deg);
    exscan_kernel<<<1, 1024, 0, stream>>>(deg, offs_p, n);
    zero_int_kernel<<<cdiv(n, TB), TB, 0, stream>>>(cursor, n);
    fill_pool_kernel<<<cdiv(nnz, TB), TB, 0, stream>>>(up_row[lvl], up_col[lvl], up_val[lvl],
                                                       nnz, offs_p, cursor, pcol, pw);
    // ---- edge CSR ----
    zero_int_kernel<<<cdiv(n, TB), TB, 0, stream>>>(deg, n);
    count_kernel<<<cdiv(e, TB), TB, 0, stream>>>(edge[lvl], e, deg);
    dinv_kernel<<<cdiv(n, TB), TB, 0, stream>>>(deg, dinv, n);
    exscan_kernel<<<1, 1024, 0, stream>>>(deg, offs_e, n);
    zero_int_kernel<<<cdiv(n, TB), TB, 0, stream>>>(cursor, n);
    fill_edge_kernel<<<cdiv(e, TB), TB, 0, stream>>>(edge[lvl], edge[lvl] + e, e,
                                                     offs_e, cursor, dinv, ecol, ew);

    const float* Wj = W_[j];
    const float* bj = b_[j];

    if (j < 3) {
      // ---- unblocked: all planes per launch (features are small) ----
      dim3 gg(cdiv(n * 32, TB), Gin);
      auto gemm = [&](const float* txp, int k, int initf) {
        const float* Wk = Wj + (size_t)k * cin * cout;
        dim3 g1(cdiv(n * 16, TB));
        if (cin == 64 && cout == 64)
          hipLaunchKernelGGL((gemm_kernel<8, 64>), g1, dim3(TB), 0, stream,
                             txp, (long long)n * 128, Wk, bj, O, (long long)n * 128, n, initf);
        else if (cin == 64 && cout == 32)
          hipLaunchKernelGGL((gemm_kernel<8, 32>), g1, dim3(TB), 0, stream,
                             txp, (long long)n * 128, Wk, bj, O, (long long)n * 128, n, initf);
        else
          hipLaunchKernelGGL((gemm_kernel<4, 32>), g1, dim3(TB), 0, stream,
                             txp, (long long)n * 128, Wk, bj, O, (long long)n * 128, n, initf);
      };
      hipLaunchKernelGGL((gather_kernel<0>), gg, dim3(TB), 0, stream,
                         (const float4*)H, offs_p, pcol, pw, (const float4*)nullptr,
                         (float4*)X, n, np * 32, n * 32);
      gemm(X, 0, 1);
      hipLaunchKernelGGL((gather_kernel<0>), gg, dim3(TB), 0, stream,
                         (const float4*)X, offs_e, ecol, ew, (const float4*)nullptr,
                         (float4*)Y, n, n * 32, n * 32);
      gemm(Y, 1, 0);
      float* p0 = X; float* p1 = Y;
      for (int k = 2; k < 6; ++k) {
        hipLaunchKernelGGL((gather_kernel<1>), gg, dim3(TB), 0, stream,
                           (const float4*)p1, offs_e, ecol, ew, (const float4*)p0,
                           (float4*)p0, n, n * 32, n * 32);
        gemm(p0, k, 0);
        float* t2 = p0; p0 = p1; p1 = t2;
      }
      elu_kernel<<<cdiv(n * 16 * cout, TB), TB, 0, stream>>>(O, H, n * 16 * cout);
    } else {
      // ---- level 0: serialize per 8-channel input group ----
      dim3 gg(cdiv(n * 32, TB));
      for (int g = 0; g < 4; ++g) {
        const float4* hplane = (const float4*)H + (size_t)g * np * 32;
        auto gemmg = [&](const float* txp, int k, int initf) {
          const float* Wk = Wj + (size_t)k * cin * cout + (size_t)g * 8 * cout;
          hipLaunchKernelGGL((gemm_kernel<1, 32>), dim3(cdiv(n * 16, TB)), dim3(TB), 0, stream,
                             txp, (long long)0, Wk, bj, O, (long long)n * 128, n, initf);
        };
        hipLaunchKernelGGL((gather_kernel<0>), gg, dim3(TB), 0, stream,
                           hplane, offs_p, pcol, pw, (const float4*)nullptr,
                           (float4*)X, n, 0, 0);
        gemmg(X, 0, (g == 0) ? 1 : 0);
        hipLaunchKernelGGL((gather_kernel<0>), gg, dim3(TB), 0, stream,
                           (const float4*)X, offs_e, ecol, ew, (const float4*)nullptr,
                           (float4*)Y, n, 0, 0);
        gemmg(Y, 1, 0);
        float* p0 = X; float* p1 = Y;
        for (int k = 2; k < 6; ++k) {
          hipLaunchKernelGGL((gather_kernel<1>), gg, dim3(TB), 0, stream,
                             (const float4*)p1, offs_e, ecol, ew, (const float4*)p0,
                             (float4*)p0, n, 0, 0);
          gemmg(p0, k, 0);
          float* t2 = p0; p0 = p1; p1 = t2;
        }
      }
      elu_kernel<<<cdiv(n * 16 * 32, TB), TB, 0, stream>>>(O, O, n * 16 * 32);
    }
  }

  // ---- final Cheb (32 -> 3) into d_out; level-0 edge CSR still resident ----
  {
    int n = N[0];
    const float* Wo = W_[4];
    const float* bo = b_[4];
    dim3 gg(cdiv(n * 32, TB));
    for (int g = 0; g < 4; ++g) {
      float* Opl = O + (size_t)g * n * 128;
      auto go = [&](const float* txp, int k, int initf) {
        const float* Wk = Wo + (size_t)k * 96 + (size_t)g * 24;
        gemm_out_kernel<<<cdiv(n * 16, TB), TB, 0, stream>>>(txp, Wk, bo, (float*)d_out, n, initf);
      };
      go(Opl, 0, (g == 0) ? 1 : 0);
      hipLaunchKernelGGL((gather_kernel<0>), gg, dim3(TB), 0, stream,
                         (const float4*)Opl, offs_e, ecol, ew, (const float4*)nullptr,
                         (float4*)X, n, 0, 0);
      go(X, 1, 0);
      float* p0 = Opl; float* p1 = X;
      for (int k = 2; k < 6; ++k) {
        hipLaunchKernelGGL((gather_kernel<1>), gg, dim3(TB), 0, stream,
                           (const float4*)p1, offs_e, ecol, ew, (const float4*)p0,
                           (float4*)p0, n, 0, 0);
        go(p0, k, 0);
        float* t2 = p0; p0 = p1; p1 = t2;
      }
    }
  }
}

// Round 3
// 2329.455 us; speedup vs baseline: 1.4679x; 1.4679x over previous
//
#include <hip/hip_runtime.h>
#include <math.h>

#define TB 256

static __device__ __forceinline__ int gtid() { return blockIdx.x * blockDim.x + threadIdx.x; }

__global__ void fill_kernel(float* __restrict__ p, int n, float v) {
  int i = gtid(); if (i < n) p[i] = v;
}

__global__ void zero_int_kernel(int* __restrict__ p, int n) {
  int i = gtid(); if (i < n) p[i] = 0;
}

__global__ void count_kernel(const int* __restrict__ rows, int e, int* __restrict__ deg) {
  int i = gtid(); if (i < e) atomicAdd(&deg[rows[i]], 1);
}

__global__ void dinv_kernel(const int* __restrict__ deg, float* __restrict__ dinv, int n) {
  int i = gtid(); if (i < n) { int d = deg[i]; dinv[i] = (d > 0) ? rsqrtf((float)d) : 0.0f; }
}

// single-block exclusive scan via wave scans; writes out[n] = total
__global__ void exscan_kernel(const int* __restrict__ in, int* __restrict__ out, int n) {
  __shared__ int wsum[16];
  __shared__ int carry_s;
  int lane = threadIdx.x & 63, wid = threadIdx.x >> 6;
  if (threadIdx.x == 0) carry_s = 0;
  __syncthreads();
  for (int base = 0; base < n; base += 1024) {
    int i = base + (int)threadIdx.x;
    int v = (i < n) ? in[i] : 0;
    int s = v;
    #pragma unroll
    for (int o = 1; o < 64; o <<= 1) {
      int t = __shfl_up(s, o, 64);
      if (lane >= o) s += t;
    }
    if (lane == 63) wsum[wid] = s;
    __syncthreads();
    if (wid == 0) {
      int ws = (lane < 16) ? wsum[lane] : 0;
      #pragma unroll
      for (int o = 1; o < 16; o <<= 1) {
        int t = __shfl_up(ws, o, 64);
        if (lane >= o) ws += t;
      }
      if (lane < 16) wsum[lane] = ws;
    }
    __syncthreads();
    int waveoff = (wid == 0) ? 0 : wsum[wid - 1];
    if (i < n) out[i] = carry_s + waveoff + s - v;
    __syncthreads();
    if (threadIdx.x == 1023) carry_s += wsum[15];
    __syncthreads();
  }
  if (threadIdx.x == 0) out[n] = carry_s;
}

__global__ void fill_edge_kernel(const int* __restrict__ rows, const int* __restrict__ cols, int e,
                                 const int* __restrict__ offs, int* __restrict__ cursor,
                                 const float* __restrict__ dinv,
                                 int* __restrict__ ccol, float* __restrict__ cw) {
  int i = gtid(); if (i >= e) return;
  int r = rows[i], c = cols[i];
  int p = atomicAdd(&cursor[r], 1);
  int idx = offs[r] + p;
  ccol[idx] = c;
  cw[idx] = dinv[r] * dinv[c];
}

__global__ void fill_pool_kernel(const int* __restrict__ rows, const int* __restrict__ cols,
                                 const float* __restrict__ vals, int e,
                                 const int* __restrict__ offs, int* __restrict__ cursor,
                                 int* __restrict__ ccol, float* __restrict__ cw) {
  int i = gtid(); if (i >= e) return;
  int r = rows[i];
  int p = atomicAdd(&cursor[r], 1);
  int idx = offs[r] + p;
  ccol[idx] = cols[i];
  cw[idx] = vals[i];
}

// out[v][j] = sum_nbr w * x[u*xs4 + xoff4 + j], j < os4 float4s per row
__global__ void pool_kernel(const float4* __restrict__ x, const int* __restrict__ offs,
                            const int* __restrict__ ccol, const float* __restrict__ cw,
                            float4* __restrict__ out, int n, int xs4, int xoff4,
                            int os4, int osh) {
  int t = gtid();
  if (t >= n * os4) return;
  int v = t >> osh, j = t & (os4 - 1);
  int s = offs[v], e = offs[v + 1];
  float ax = 0.f, ay = 0.f, az = 0.f, aw = 0.f;
  for (int i = s; i < e; ++i) {
    float w = cw[i];
    float4 xv = x[(long long)ccol[i] * xs4 + xoff4 + j];
    ax += w * xv.x; ay += w * xv.y; az += w * xv.z; aw += w * xv.w;
  }
  float4 o; o.x = ax; o.y = ay; o.z = az; o.w = aw;
  out[t] = o;
}

// Fused Clenshaw step for deblock convs. Layout: rows of CIN/COUT floats per (v,bi).
// mode 0 INIT:   b2o = X*Wk
// mode 1 SECOND: b2o = X*Wk + 2*gather(b1)
// mode 2 MID:    b2o = X*Wk + 2*gather(b1) - b2o      (in-place)
// mode 3 FINAL:  b2o = ELU(X*Wk + gather(b1) - b2o + bias)
template<int CIN, int COUT>
__global__ void cheb_deblock_kernel(const float* __restrict__ X,
                                    const float* __restrict__ b1,
                                    float* __restrict__ b2o,
                                    const float* __restrict__ Wk,
                                    const float* __restrict__ bias,
                                    const int* __restrict__ offs,
                                    const int* __restrict__ ccol,
                                    const float* __restrict__ cw,
                                    int n, int BI, int mode) {
  __shared__ float sW[CIN * COUT];
  for (int i = threadIdx.x; i < CIN * COUT; i += blockDim.x) sW[i] = Wk[i];
  __syncthreads();
  int t = gtid();
  if (t >= n * BI) return;
  int v = t / BI;
  int bi = t - v * BI;
  constexpr int C4 = COUT / 4;
  float4 acc[C4];
  #pragma unroll
  for (int d = 0; d < C4; ++d) acc[d] = make_float4(0.f, 0.f, 0.f, 0.f);
  const float4* Xr = (const float4*)(X + (long long)t * CIN);
  for (int c4 = 0; c4 < CIN / 4; ++c4) {
    float4 xv = Xr[c4];
    const float4* w0 = (const float4*)&sW[(c4 * 4 + 0) * COUT];
    const float4* w1 = (const float4*)&sW[(c4 * 4 + 1) * COUT];
    const float4* w2 = (const float4*)&sW[(c4 * 4 + 2) * COUT];
    const float4* w3 = (const float4*)&sW[(c4 * 4 + 3) * COUT];
    #pragma unroll
    for (int d = 0; d < C4; ++d) {
      float4 a = acc[d], p0 = w0[d], p1 = w1[d], p2 = w2[d], p3 = w3[d];
      a.x += xv.x * p0.x + xv.y * p1.x + xv.z * p2.x + xv.w * p3.x;
      a.y += xv.x * p0.y + xv.y * p1.y + xv.z * p2.y + xv.w * p3.y;
      a.z += xv.x * p0.z + xv.y * p1.z + xv.z * p2.z + xv.w * p3.z;
      a.w += xv.x * p0.w + xv.y * p1.w + xv.z * p2.w + xv.w * p3.w;
      acc[d] = a;
    }
  }
  if (mode >= 1) {
    float sc = (mode == 3) ? 1.f : 2.f;
    int s = offs[v], e = offs[v + 1];
    for (int i = s; i < e; ++i) {
      float w = cw[i] * sc;
      const float4* br = (const float4*)(b1 + ((long long)ccol[i] * BI + bi) * COUT);
      #pragma unroll
      for (int d = 0; d < C4; ++d) {
        float4 bv = br[d];
        acc[d].x += w * bv.x; acc[d].y += w * bv.y;
        acc[d].z += w * bv.z; acc[d].w += w * bv.w;
      }
    }
  }
  float4* Or = (float4*)(b2o + (long long)t * COUT);
  if (mode >= 2) {
    #pragma unroll
    for (int d = 0; d < C4; ++d) {
      float4 bv = Or[d];
      acc[d].x -= bv.x; acc[d].y -= bv.y; acc[d].z -= bv.z; acc[d].w -= bv.w;
    }
  }
  if (mode == 3) {
    const float4* bs = (const float4*)bias;
    #pragma unroll
    for (int d = 0; d < C4; ++d) {
      float4 bb = bs[d];
      float4 a = acc[d];
      a.x += bb.x; a.y += bb.y; a.z += bb.z; a.w += bb.w;
      a.x = a.x > 0.f ? a.x : expm1f(a.x);
      a.y = a.y > 0.f ? a.y : expm1f(a.y);
      a.z = a.z > 0.f ? a.z : expm1f(a.z);
      a.w = a.w > 0.f ? a.w : expm1f(a.w);
      acc[d] = a;
    }
  }
  #pragma unroll
  for (int d = 0; d < C4; ++d) Or[d] = acc[d];
}

// Clenshaw step for the output conv (CIN=32 -> 3), BI=4 batch slice.
// modes as above; mode 3 writes dout[(bi*n + v)*3] (dout pre-offset by batch group).
__global__ void cheb_out_kernel(const float* __restrict__ X,
                                const float* __restrict__ b1,
                                float* __restrict__ b2o,
                                const float* __restrict__ Wk,
                                const float* __restrict__ bias,
                                const int* __restrict__ offs,
                                const int* __restrict__ ccol,
                                const float* __restrict__ cw,
                                int n, float* __restrict__ dout, int mode) {
  __shared__ float sW[32 * 3];
  __shared__ float sb[3];
  for (int i = threadIdx.x; i < 96; i += blockDim.x) sW[i] = Wk[i];
  if (threadIdx.x < 3) sb[threadIdx.x] = bias[threadIdx.x];
  __syncthreads();
  int t = gtid();
  if (t >= n * 4) return;
  int v = t >> 2, bi = t & 3;
  float a0 = 0.f, a1 = 0.f, a2 = 0.f;
  const float4* Xr = (const float4*)(X + (long long)t * 32);
  #pragma unroll
  for (int c4 = 0; c4 < 8; ++c4) {
    float4 xv = Xr[c4];
    const float* w = &sW[c4 * 12];
    a0 += xv.x * w[0] + xv.y * w[3] + xv.z * w[6] + xv.w * w[9];
    a1 += xv.x * w[1] + xv.y * w[4] + xv.z * w[7] + xv.w * w[10];
    a2 += xv.x * w[2] + xv.y * w[5] + xv.z * w[8] + xv.w * w[11];
  }
  if (mode >= 1) {
    float sc = (mode == 3) ? 1.f : 2.f;
    int s = offs[v], e = offs[v + 1];
    for (int i = s; i < e; ++i) {
      float w = cw[i] * sc;
      const float* br = b1 + ((long long)ccol[i] * 4 + bi) * 3;
      a0 += w * br[0]; a1 += w * br[1]; a2 += w * br[2];
    }
  }
  if (mode >= 2) {
    const float* b2r = b2o + (long long)t * 3;
    a0 -= b2r[0]; a1 -= b2r[1]; a2 -= b2r[2];
  }
  if (mode == 3) {
    a0 += sb[0]; a1 += sb[1]; a2 += sb[2];
    float* o = dout + ((long long)bi * n + v) * 3;
    o[0] = a0; o[1] = a1; o[2] = a2;
  } else {
    float* o = b2o + (long long)t * 3;
    o[0] = a0; o[1] = a1; o[2] = a2;
  }
}

// h4[(v*16+b)*64 + c] = x[b]·lin_w[:, v*64+c] + lin_b[v*64+c]
__global__ void linear_kernel(const float* __restrict__ x, const float* __restrict__ w,
                              const float* __restrict__ bias, float* __restrict__ out) {
  int t = gtid();
  const int TOT = 157 * 16 * 64;
  if (t >= TOT) return;
  int c = t & 63;
  int b = (t >> 6) & 15;
  int v = t >> 10;
  int colw = v * 64 + c;
  float acc = bias[colw];
  const float* xr = x + b * 128;
  for (int k = 0; k < 128; ++k) acc += xr[k] * w[k * 10048 + colw];
  out[t] = acc;
}

extern "C" void kernel_launch(void* const* d_in, const int* in_sizes, int n_in,
                              void* d_out, int out_size, void* d_ws, size_t ws_size,
                              hipStream_t stream) {
  const int N[5] = {40000, 10000, 2500, 625, 157};
  const int E[4] = {240000, 60000, 15000, 3750};
  const int NNZ[4] = {120000, 30000, 7500, 1875};

  const float* x     = (const float*)d_in[0];
  const float* lin_w = (const float*)d_in[1];
  const float* lin_b = (const float*)d_in[2];
  const int* edge[4] = {(const int*)d_in[3], (const int*)d_in[4], (const int*)d_in[5], (const int*)d_in[6]};
  const int* up_row[4]; const int* up_col[4]; const float* up_val[4];
  for (int i = 0; i < 4; ++i) {
    up_row[i] = (const int*)d_in[7 + 3 * i];
    up_col[i] = (const int*)d_in[8 + 3 * i];
    up_val[i] = (const float*)d_in[9 + 3 * i];
  }
  const float* W_[5] = {(const float*)d_in[19], (const float*)d_in[21], (const float*)d_in[23],
                        (const float*)d_in[25], (const float*)d_in[27]};
  const float* b_[5] = {(const float*)d_in[20], (const float*)d_in[22], (const float*)d_in[24],
                        (const float*)d_in[26], (const float*)d_in[28]};

  char* ws = (char*)d_ws;
  size_t off = 0;
  auto alloc = [&](size_t bytes) -> void* {
    void* p = ws + off;
    off = (off + bytes + 255) & ~(size_t)255;
    return p;
  };
  auto cdiv = [](int a, int b) { return (a + b - 1) / b; };

  // 4 rotating 20.48 MB slots (max: [10000][16][32] or [40000][4][32] fp32)
  float* slot[4];
  for (int i = 0; i < 4; ++i) slot[i] = (float*)alloc(20480000ull);
  int*   deg    = (int*)alloc(40000 * 4);
  int*   cursor = (int*)alloc(40000 * 4);
  int*   offs_p = (int*)alloc(40001 * 4);
  int*   offs_e = (int*)alloc(40001 * 4);
  float* dinv   = (float*)alloc(40000 * 4);
  int*   pcol   = (int*)alloc(120000 * 4);
  float* pw     = (float*)alloc(120000 * 4);
  int*   ecol   = (int*)alloc(240000 * 4);
  float* ew     = (float*)alloc(240000 * 4);

  if (off > ws_size) {
    fill_kernel<<<cdiv(out_size, TB), TB, 0, stream>>>((float*)d_out, out_size,
                                                       (float)(ws_size >> 20));
    return;
  }

  auto build_pool_csr = [&](int lvl) {
    int n = N[lvl], nnz = NNZ[lvl];
    zero_int_kernel<<<cdiv(n, TB), TB, 0, stream>>>(deg, n);
    count_kernel<<<cdiv(nnz, TB), TB, 0, stream>>>(up_row[lvl], nnz, deg);
    exscan_kernel<<<1, 1024, 0, stream>>>(deg, offs_p, n);
    zero_int_kernel<<<cdiv(n, TB), TB, 0, stream>>>(cursor, n);
    fill_pool_kernel<<<cdiv(nnz, TB), TB, 0, stream>>>(up_row[lvl], up_col[lvl], up_val[lvl],
                                                       nnz, offs_p, cursor, pcol, pw);
  };
  auto build_edge_csr = [&](int lvl) {
    int n = N[lvl], e = E[lvl];
    zero_int_kernel<<<cdiv(n, TB), TB, 0, stream>>>(deg, n);
    count_kernel<<<cdiv(e, TB), TB, 0, stream>>>(edge[lvl], e, deg);
    dinv_kernel<<<cdiv(n, TB), TB, 0, stream>>>(deg, dinv, n);
    exscan_kernel<<<1, 1024, 0, stream>>>(deg, offs_e, n);
    zero_int_kernel<<<cdiv(n, TB), TB, 0, stream>>>(cursor, n);
    fill_edge_kernel<<<cdiv(e, TB), TB, 0, stream>>>(edge[lvl], edge[lvl] + e, e,
                                                     offs_e, cursor, dinv, ecol, ew);
  };

  // latent -> h4 [157][16][64] in slot[0]
  linear_kernel<<<cdiv(157 * 16 * 64, TB), TB, 0, stream>>>(x, lin_w, lin_b, slot[0]);
  float* H = slot[0];
  float* A = slot[1];
  float* B = slot[2];
  float* C = slot[3];

  const int CINA[4]  = {64, 64, 32, 32};
  const int COUTA[4] = {64, 32, 32, 32};

  // ---- upper levels: deblocks j=0..2 on meshes 3,2,1, full batch (BI=16) ----
  for (int j = 0; j < 3; ++j) {
    int lvl = 3 - j;
    int n = N[lvl];
    int cin = CINA[j], cout = COUTA[j];
    int os4 = 16 * cin / 4;
    int osh = (os4 == 256) ? 8 : 7;
    int xs4 = os4;  // previous h has same channel count = cin

    build_pool_csr(lvl);
    build_edge_csr(lvl);

    pool_kernel<<<cdiv(n * os4, TB), TB, 0, stream>>>(
        (const float4*)H, offs_p, pcol, pw, (float4*)A, n, xs4, 0, os4, osh);

    int rows = n * 16;
    dim3 g(cdiv(rows, TB));
    auto step = [&](const float* b1, float* b2o, int k, int mode) {
      const float* Wk = W_[j] + (size_t)k * cin * cout;
      if (cin == 64 && cout == 64)
        hipLaunchKernelGGL((cheb_deblock_kernel<64, 64>), g, dim3(TB), 0, stream,
                           A, b1, b2o, Wk, b_[j], offs_e, ecol, ew, n, 16, mode);
      else if (cin == 64 && cout == 32)
        hipLaunchKernelGGL((cheb_deblock_kernel<64, 32>), g, dim3(TB), 0, stream,
                           A, b1, b2o, Wk, b_[j], offs_e, ecol, ew, n, 16, mode);
      else
        hipLaunchKernelGGL((cheb_deblock_kernel<32, 32>), g, dim3(TB), 0, stream,
                           A, b1, b2o, Wk, b_[j], offs_e, ecol, ew, n, 16, mode);
    };
    step(nullptr, B, 5, 0);
    step(B, C, 4, 1);
    step(C, B, 3, 2);
    step(B, C, 2, 2);
    step(C, B, 1, 2);
    step(B, C, 0, 3);   // h_new (ELU'd) in C

    float* tmp = H; H = C; C = tmp;
  }

  // ---- level 0: deblock j=3 (32->32) + output conv (32->3), batch-split 4x4 ----
  build_pool_csr(0);
  build_edge_csr(0);
  {
    int n = N[0];
    dim3 g(cdiv(n * 4, TB));
    for (int bg = 0; bg < 4; ++bg) {
      // pool h1 slice -> A  ([40000][4][32])
      pool_kernel<<<cdiv(n * 32, TB), TB, 0, stream>>>(
          (const float4*)H, offs_p, pcol, pw, (float4*)A, n, 128, bg * 32, 32, 5);
      // deblock Clenshaw, X=A
      auto dstep = [&](const float* b1, float* b2o, int k, int mode) {
        const float* Wk = W_[3] + (size_t)k * 32 * 32;
        hipLaunchKernelGGL((cheb_deblock_kernel<32, 32>), g, dim3(TB), 0, stream,
                           A, b1, b2o, Wk, b_[3], offs_e, ecol, ew, n, 4, mode);
      };
      dstep(nullptr, B, 5, 0);
      dstep(B, C, 4, 1);
      dstep(C, B, 3, 2);
      dstep(B, C, 2, 2);
      dstep(C, B, 1, 2);
      dstep(B, C, 0, 3);   // h0(bg) in C
      // output Clenshaw, X=C, small b-buffers in A/B (1.92 MB each)
      float* doutg = (float*)d_out + (size_t)bg * 4 * n * 3;
      auto ostep = [&](const float* b1, float* b2o, int k, int mode) {
        const float* Wk = W_[4] + (size_t)k * 96;
        cheb_out_kernel<<<g, dim3(TB), 0, stream>>>(C, b1, b2o, Wk, b_[4],
                                                    offs_e, ecol, ew, n, doutg, mode);
      };
      ostep(nullptr, A, 5, 0);
      ostep(A, B, 4, 1);
      ostep(B, A, 3, 2);
      ostep(A, B, 2, 2);
      ostep(B, A, 1, 2);
      ostep(A, B, 0, 3);
    }
  }
}

// Round 4
// 1448.896 us; speedup vs baseline: 2.3599x; 1.6077x over previous
//
#include <hip/hip_runtime.h>
#include <math.h>

#define TB 256

static __device__ __forceinline__ int gtid() { return blockIdx.x * blockDim.x + threadIdx.x; }

static __device__ __forceinline__ void fma4(float4& a, float s, const float4 b) {
  a.x = fmaf(s, b.x, a.x); a.y = fmaf(s, b.y, a.y);
  a.z = fmaf(s, b.z, a.z); a.w = fmaf(s, b.w, a.w);
}

__global__ void fill_kernel(float* __restrict__ p, int n, float v) {
  int i = gtid(); if (i < n) p[i] = v;
}

__global__ void zero_int_kernel(int* __restrict__ p, int n) {
  int i = gtid(); if (i < n) p[i] = 0;
}

__global__ void count_kernel(const int* __restrict__ rows, int e, int* __restrict__ deg) {
  int i = gtid(); if (i < e) atomicAdd(&deg[rows[i]], 1);
}

struct Seg8 { int db[8]; int ob[8]; int nn[8]; };

// 8 independent exclusive scans, one block each; also zeroes cursor_all and
// writes total at offs[n].
__global__ void exscan8_kernel(const int* __restrict__ deg_all, int* __restrict__ offs_all,
                               int* __restrict__ cursor_all, Seg8 sg) {
  int blk = blockIdx.x;
  const int* in = deg_all + sg.db[blk];
  int* out = offs_all + sg.ob[blk];
  int* cur = cursor_all + sg.db[blk];
  int n = sg.nn[blk];
  __shared__ int wsum[16];
  __shared__ int carry_s;
  int lane = threadIdx.x & 63, wid = threadIdx.x >> 6;
  if (threadIdx.x == 0) carry_s = 0;
  __syncthreads();
  for (int base = 0; base < n; base += 1024) {
    int i = base + (int)threadIdx.x;
    int v = (i < n) ? in[i] : 0;
    int s = v;
    #pragma unroll
    for (int o = 1; o < 64; o <<= 1) {
      int t = __shfl_up(s, o, 64);
      if (lane >= o) s += t;
    }
    if (lane == 63) wsum[wid] = s;
    __syncthreads();
    if (wid == 0) {
      int ws = (lane < 16) ? wsum[lane] : 0;
      #pragma unroll
      for (int o = 1; o < 16; o <<= 1) {
        int t = __shfl_up(ws, o, 64);
        if (lane >= o) ws += t;
      }
      if (lane < 16) wsum[lane] = ws;
    }
    __syncthreads();
    int waveoff = (wid == 0) ? 0 : wsum[wid - 1];
    if (i < n) { out[i] = carry_s + waveoff + s - v; cur[i] = 0; }
    __syncthreads();
    if (threadIdx.x == 1023) carry_s += wsum[15];
    __syncthreads();
  }
  if (threadIdx.x == 0) out[n] = carry_s;
}

__global__ void fill_edge_kernel(const int* __restrict__ rows, const int* __restrict__ cols, int e,
                                 const int* __restrict__ offs, int* __restrict__ cursor,
                                 const int* __restrict__ deg,
                                 int* __restrict__ ccol, float* __restrict__ cw) {
  int i = gtid(); if (i >= e) return;
  int r = rows[i], c = cols[i];
  int p = atomicAdd(&cursor[r], 1);
  int idx = offs[r] + p;
  int dc = deg[c];
  float w = rsqrtf((float)deg[r]) * (dc > 0 ? rsqrtf((float)dc) : 0.f);
  ccol[idx] = c;
  cw[idx] = w;
}

__global__ void fill_pool_kernel(const int* __restrict__ rows, const int* __restrict__ cols,
                                 const float* __restrict__ vals, int e,
                                 const int* __restrict__ offs, int* __restrict__ cursor,
                                 int* __restrict__ ccol, float* __restrict__ cw) {
  int i = gtid(); if (i >= e) return;
  int r = rows[i];
  int p = atomicAdd(&cursor[r], 1);
  int idx = offs[r] + p;
  ccol[idx] = cols[i];
  cw[idx] = vals[i];
}

// out[v][j] = sum_nbr w * x[u*xs4 + xoff4 + j], j < os4 float4s per row
__global__ void pool_kernel(const float4* __restrict__ x, const int* __restrict__ offs,
                            const int* __restrict__ ccol, const float* __restrict__ cw,
                            float4* __restrict__ out, int n, int xs4, int xoff4,
                            int os4, int osh) {
  int t = gtid();
  if (t >= n * os4) return;
  int v = t >> osh, j = t & (os4 - 1);
  int s = offs[v], e = offs[v + 1];
  float4 a = {0.f, 0.f, 0.f, 0.f};
  for (int i = s; i < e; ++i) {
    fma4(a, cw[i], x[(long long)ccol[i] * xs4 + xoff4 + j]);
  }
  out[t] = a;
}

// Channel-split fused Clenshaw step. Thread = (r, cs): r = v*BI+bi, cs = 8-ch slice.
// mode 0: b2o = X*Wk ; 1: += 2*gather(b1) ; 2: ... - b2o (in-place) ;
// 3: ELU(X*Wk + gather(b1) - b2o + bias)
template<int CIN, int COUT>
__global__ void cheb_step_kernel(const float* __restrict__ X,
                                 const float* __restrict__ b1,
                                 float* __restrict__ b2o,
                                 const float* __restrict__ Wk,
                                 const float* __restrict__ bias,
                                 const int* __restrict__ offs,
                                 const int* __restrict__ ccol,
                                 const float* __restrict__ cw,
                                 int n, int LB, int mode) {
  constexpr int CS = COUT / 8;
  constexpr int LCS = (CS == 8) ? 3 : 2;
  constexpr int W4 = COUT / 4;
  __shared__ float sW[CIN * COUT];
  for (int i = threadIdx.x; i < CIN * COUT; i += blockDim.x) sW[i] = Wk[i];
  __syncthreads();
  int t = gtid();
  int BI = 1 << LB;
  if (t >= n * BI * CS) return;
  int cs = t & (CS - 1);
  int r = t >> LCS;
  int v = r >> LB;
  int bi = r & (BI - 1);
  float4 a0 = {0.f, 0.f, 0.f, 0.f}, a1 = {0.f, 0.f, 0.f, 0.f};
  const float4* Xr = (const float4*)(X + (long long)r * CIN);
  const float4* wbase = ((const float4*)sW) + cs * 2;
  #pragma unroll
  for (int c4 = 0; c4 < CIN / 4; ++c4) {
    float4 xv = Xr[c4];
    const float4* w = wbase + (c4 * 4) * W4;
    fma4(a0, xv.x, w[0]); fma4(a1, xv.x, w[1]); w += W4;
    fma4(a0, xv.y, w[0]); fma4(a1, xv.y, w[1]); w += W4;
    fma4(a0, xv.z, w[0]); fma4(a1, xv.z, w[1]); w += W4;
    fma4(a0, xv.w, w[0]); fma4(a1, xv.w, w[1]);
  }
  if (mode >= 1) {
    float sc = (mode == 3) ? 1.f : 2.f;
    int s = offs[v], e = offs[v + 1];
    const float4* b14 = (const float4*)b1;
    for (int i = s; i < e; ++i) {
      float w = cw[i] * sc;
      long long rb = (long long)((ccol[i] << LB) | bi) * W4 + cs * 2;
      fma4(a0, w, b14[rb]); fma4(a1, w, b14[rb + 1]);
    }
  }
  float4* Or = ((float4*)b2o) + (long long)r * W4 + cs * 2;
  if (mode >= 2) {
    float4 p0 = Or[0], p1 = Or[1];
    a0.x -= p0.x; a0.y -= p0.y; a0.z -= p0.z; a0.w -= p0.w;
    a1.x -= p1.x; a1.y -= p1.y; a1.z -= p1.z; a1.w -= p1.w;
  }
  if (mode == 3) {
    const float* bs = bias + cs * 8;
    a0.x += bs[0]; a0.y += bs[1]; a0.z += bs[2]; a0.w += bs[3];
    a1.x += bs[4]; a1.y += bs[5]; a1.z += bs[6]; a1.w += bs[7];
    a0.x = a0.x > 0.f ? a0.x : expm1f(a0.x);
    a0.y = a0.y > 0.f ? a0.y : expm1f(a0.y);
    a0.z = a0.z > 0.f ? a0.z : expm1f(a0.z);
    a0.w = a0.w > 0.f ? a0.w : expm1f(a0.w);
    a1.x = a1.x > 0.f ? a1.x : expm1f(a1.x);
    a1.y = a1.y > 0.f ? a1.y : expm1f(a1.y);
    a1.z = a1.z > 0.f ? a1.z : expm1f(a1.z);
    a1.w = a1.w > 0.f ? a1.w : expm1f(a1.w);
  }
  Or[0] = a0; Or[1] = a1;
}

// c_all[r][k][3] = X[r]·Wout[k]  for all 6 k in one pass (X read once)
__global__ void gemm_out_all_kernel(const float* __restrict__ X, const float* __restrict__ W,
                                    float* __restrict__ c_all, int n) {
  __shared__ float sW[576];
  for (int i = threadIdx.x; i < 576; i += blockDim.x) sW[i] = W[i];
  __syncthreads();
  int r = gtid();
  if (r >= n * 4) return;
  const float4* Xr = (const float4*)(X + (long long)r * 32);
  float xa[32];
  #pragma unroll
  for (int c4 = 0; c4 < 8; ++c4) {
    float4 xv = Xr[c4];
    xa[c4 * 4 + 0] = xv.x; xa[c4 * 4 + 1] = xv.y;
    xa[c4 * 4 + 2] = xv.z; xa[c4 * 4 + 3] = xv.w;
  }
  float acc[18];
  #pragma unroll
  for (int i = 0; i < 18; ++i) acc[i] = 0.f;
  #pragma unroll
  for (int c = 0; c < 32; ++c) {
    float xc = xa[c];
    #pragma unroll
    for (int k = 0; k < 6; ++k) {
      acc[k * 3 + 0] = fmaf(xc, sW[k * 96 + c * 3 + 0], acc[k * 3 + 0]);
      acc[k * 3 + 1] = fmaf(xc, sW[k * 96 + c * 3 + 1], acc[k * 3 + 1]);
      acc[k * 3 + 2] = fmaf(xc, sW[k * 96 + c * 3 + 2], acc[k * 3 + 2]);
    }
  }
  float* o = c_all + (long long)r * 18;
  #pragma unroll
  for (int i = 0; i < 18; ++i) o[i] = acc[i];
}

// Clenshaw step on the tiny 3-channel buffers; mode 3 writes dout[(bi*n+v)*3]
__global__ void cheb_out_step_kernel(const float* __restrict__ c_all, int k,
                                     const float* __restrict__ b1,
                                     float* __restrict__ b2o,
                                     const float* __restrict__ bias,
                                     const int* __restrict__ offs,
                                     const int* __restrict__ ccol,
                                     const float* __restrict__ cw,
                                     int n, float* __restrict__ dout, int mode) {
  int r = gtid();
  if (r >= n * 4) return;
  int v = r >> 2, bi = r & 3;
  const float* cr = c_all + (long long)r * 18 + k * 3;
  float a0 = cr[0], a1 = cr[1], a2 = cr[2];
  if (mode >= 1) {
    float sc = (mode == 3) ? 1.f : 2.f;
    int s = offs[v], e = offs[v + 1];
    for (int i = s; i < e; ++i) {
      float w = cw[i] * sc;
      const float* br = b1 + (long long)((ccol[i] << 2) | bi) * 3;
      a0 = fmaf(w, br[0], a0); a1 = fmaf(w, br[1], a1); a2 = fmaf(w, br[2], a2);
    }
  }
  if (mode >= 2) {
    const float* p = b2o + (long long)r * 3;
    a0 -= p[0]; a1 -= p[1]; a2 -= p[2];
  }
  if (mode == 3) {
    a0 += bias[0]; a1 += bias[1]; a2 += bias[2];
    float* o = dout + ((long long)bi * n + v) * 3;
    o[0] = a0; o[1] = a1; o[2] = a2;
  } else {
    float* o = b2o + (long long)r * 3;
    o[0] = a0; o[1] = a1; o[2] = a2;
  }
}

// h4[(v*16+b)*64 + c] = x[b]·lin_w[:, v*64+c] + lin_b[v*64+c]
__global__ void linear_kernel(const float* __restrict__ x, const float* __restrict__ w,
                              const float* __restrict__ bias, float* __restrict__ out) {
  int t = gtid();
  const int TOT = 157 * 16 * 64;
  if (t >= TOT) return;
  int c = t & 63;
  int b = (t >> 6) & 15;
  int v = t >> 10;
  int colw = v * 64 + c;
  float acc = bias[colw];
  const float* xr = x + b * 128;
  for (int k = 0; k < 128; ++k) acc = fmaf(xr[k], w[k * 10048 + colw], acc);
  out[t] = acc;
}

extern "C" void kernel_launch(void* const* d_in, const int* in_sizes, int n_in,
                              void* d_out, int out_size, void* d_ws, size_t ws_size,
                              hipStream_t stream) {
  const int N[4] = {40000, 10000, 2500, 625};
  const int E[4] = {240000, 60000, 15000, 3750};
  const int NNZ[4] = {120000, 30000, 7500, 1875};
  const int PB[4] = {0, 120000, 150000, 157500};   // pool col/val bases
  const int EB[4] = {0, 240000, 300000, 315000};   // edge col/val bases
  const int DP[4] = {0, 40000, 50000, 52500};      // deg bases (pool)
  const int DE[4] = {53125, 93125, 103125, 105625};
  const int OP[4] = {0, 40001, 50002, 52504};      // offs bases (pool)
  const int OE[4] = {53130, 93131, 103132, 105634};

  const float* x     = (const float*)d_in[0];
  const float* lin_w = (const float*)d_in[1];
  const float* lin_b = (const float*)d_in[2];
  const int* edge[4] = {(const int*)d_in[3], (const int*)d_in[4], (const int*)d_in[5], (const int*)d_in[6]};
  const int* up_row[4]; const int* up_col[4]; const float* up_val[4];
  for (int i = 0; i < 4; ++i) {
    up_row[i] = (const int*)d_in[7 + 3 * i];
    up_col[i] = (const int*)d_in[8 + 3 * i];
    up_val[i] = (const float*)d_in[9 + 3 * i];
  }
  const float* W_[5] = {(const float*)d_in[19], (const float*)d_in[21], (const float*)d_in[23],
                        (const float*)d_in[25], (const float*)d_in[27]};
  const float* b_[5] = {(const float*)d_in[20], (const float*)d_in[22], (const float*)d_in[24],
                        (const float*)d_in[26], (const float*)d_in[28]};

  char* ws = (char*)d_ws;
  size_t off = 0;
  auto alloc = [&](size_t bytes) -> void* {
    void* p = ws + off;
    off = (off + bytes + 255) & ~(size_t)255;
    return p;
  };
  auto cdiv = [](int a, int b) { return (a + b - 1) / b; };

  float* slot[4];
  for (int i = 0; i < 4; ++i) slot[i] = (float*)alloc(20480000ull);  // 20.48 MB each
  float* c_all = (float*)alloc((size_t)40000 * 4 * 18 * 4);          // 11.52 MB
  float* ob1   = (float*)alloc((size_t)40000 * 4 * 3 * 4);           // 1.92 MB
  float* ob2   = (float*)alloc((size_t)40000 * 4 * 3 * 4);
  int* deg_all    = (int*)alloc(106250 * 4);
  int* cursor_all = (int*)alloc(106250 * 4);
  int* offs_all   = (int*)alloc(106260 * 4);
  int* pcol  = (int*)alloc(159375 * 4);
  float* pw  = (float*)alloc(159375 * 4);
  int* ecol  = (int*)alloc(318750 * 4);
  float* ew  = (float*)alloc(318750 * 4);

  if (off > ws_size) {
    fill_kernel<<<cdiv(out_size, TB), TB, 0, stream>>>((float*)d_out, out_size,
                                                       (float)(ws_size >> 20));
    return;
  }

  // ---- batched CSR build for all levels ----
  zero_int_kernel<<<cdiv(106250, TB), TB, 0, stream>>>(deg_all, 106250);
  for (int l = 0; l < 4; ++l)
    count_kernel<<<cdiv(NNZ[l], TB), TB, 0, stream>>>(up_row[l], NNZ[l], deg_all + DP[l]);
  for (int l = 0; l < 4; ++l)
    count_kernel<<<cdiv(E[l], TB), TB, 0, stream>>>(edge[l], E[l], deg_all + DE[l]);
  Seg8 sg;
  for (int l = 0; l < 4; ++l) {
    sg.db[l] = DP[l]; sg.ob[l] = OP[l]; sg.nn[l] = N[l];
    sg.db[l + 4] = DE[l]; sg.ob[l + 4] = OE[l]; sg.nn[l + 4] = N[l];
  }
  exscan8_kernel<<<8, 1024, 0, stream>>>(deg_all, offs_all, cursor_all, sg);
  for (int l = 0; l < 4; ++l)
    fill_pool_kernel<<<cdiv(NNZ[l], TB), TB, 0, stream>>>(
        up_row[l], up_col[l], up_val[l], NNZ[l],
        offs_all + OP[l], cursor_all + DP[l], pcol + PB[l], pw + PB[l]);
  for (int l = 0; l < 4; ++l)
    fill_edge_kernel<<<cdiv(E[l], TB), TB, 0, stream>>>(
        edge[l], edge[l] + E[l], E[l],
        offs_all + OE[l], cursor_all + DE[l], deg_all + DE[l], ecol + EB[l], ew + EB[l]);

  // latent -> h4 [157][16][64]
  linear_kernel<<<cdiv(157 * 16 * 64, TB), TB, 0, stream>>>(x, lin_w, lin_b, slot[0]);
  float* H = slot[0];
  float* A = slot[1];
  float* B = slot[2];
  float* C = slot[3];

  const int CINA[3]  = {64, 64, 32};
  const int COUTA[3] = {64, 32, 32};

  // ---- deblocks j=0..2 on meshes 3,2,1, full batch (BI=16) ----
  for (int j = 0; j < 3; ++j) {
    int lvl = 3 - j;
    int n = N[lvl];
    int cin = CINA[j], cout = COUTA[j];
    int os4 = 16 * cin / 4;
    int osh = (os4 == 256) ? 8 : 7;
    const int* offs_p = offs_all + OP[lvl];
    const int* offs_e = offs_all + OE[lvl];
    const int* pc = pcol + PB[lvl]; const float* pv = pw + PB[lvl];
    const int* ec = ecol + EB[lvl]; const float* ev = ew + EB[lvl];

    pool_kernel<<<cdiv(n * os4, TB), TB, 0, stream>>>(
        (const float4*)H, offs_p, pc, pv, (float4*)A, n, os4, 0, os4, osh);

    int cs = cout / 8;
    dim3 g(cdiv(n * 16 * cs, TB));
    auto step = [&](const float* b1, float* b2o, int k, int mode) {
      const float* Wk = W_[j] + (size_t)k * cin * cout;
      if (cin == 64 && cout == 64)
        hipLaunchKernelGGL((cheb_step_kernel<64, 64>), g, dim3(TB), 0, stream,
                           A, b1, b2o, Wk, b_[j], offs_e, ec, ev, n, 4, mode);
      else if (cin == 64 && cout == 32)
        hipLaunchKernelGGL((cheb_step_kernel<64, 32>), g, dim3(TB), 0, stream,
                           A, b1, b2o, Wk, b_[j], offs_e, ec, ev, n, 4, mode);
      else
        hipLaunchKernelGGL((cheb_step_kernel<32, 32>), g, dim3(TB), 0, stream,
                           A, b1, b2o, Wk, b_[j], offs_e, ec, ev, n, 4, mode);
    };
    step(nullptr, B, 5, 0);
    step(B, C, 4, 1);
    step(C, B, 3, 2);
    step(B, C, 2, 2);
    step(C, B, 1, 2);
    step(B, C, 0, 3);   // h_new (ELU'd) in C

    float* tmp = H; H = C; C = tmp;
  }

  // ---- level 0: deblock j=3 (32->32) + output conv (32->3), batch-split 4x4 ----
  {
    int n = N[0];
    const int* offs_p = offs_all + OP[0];
    const int* offs_e = offs_all + OE[0];
    const int* pc = pcol + PB[0]; const float* pv = pw + PB[0];
    const int* ec = ecol + EB[0]; const float* ev = ew + EB[0];
    dim3 g(cdiv(n * 4 * 4, TB));
    dim3 go(cdiv(n * 4, TB));
    for (int bg = 0; bg < 4; ++bg) {
      pool_kernel<<<cdiv(n * 32, TB), TB, 0, stream>>>(
          (const float4*)H, offs_p, pc, pv, (float4*)A, n, 128, bg * 32, 32, 5);
      auto dstep = [&](const float* b1, float* b2o, int k, int mode) {
        const float* Wk = W_[3] + (size_t)k * 32 * 32;
        hipLaunchKernelGGL((cheb_step_kernel<32, 32>), g, dim3(TB), 0, stream,
                           A, b1, b2o, Wk, b_[3], offs_e, ec, ev, n, 2, mode);
      };
      dstep(nullptr, B, 5, 0);
      dstep(B, C, 4, 1);
      dstep(C, B, 3, 2);
      dstep(B, C, 2, 2);
      dstep(C, B, 1, 2);
      dstep(B, C, 0, 3);   // h0(bg) in C

      gemm_out_all_kernel<<<go, dim3(TB), 0, stream>>>(C, W_[4], c_all, n);
      float* doutg = (float*)d_out + (size_t)bg * 4 * n * 3;
      auto ostep = [&](const float* b1, float* b2o, int k, int mode) {
        cheb_out_step_kernel<<<go, dim3(TB), 0, stream>>>(
            c_all, k, b1, b2o, b_[4], offs_e, ec, ev, n, doutg, mode);
      };
      ostep(nullptr, ob1, 5, 0);
      ostep(ob1, ob2, 4, 1);
      ostep(ob2, ob1, 3, 2);
      ostep(ob1, ob2, 2, 2);
      ostep(ob2, ob1, 1, 2);
      ostep(ob1, ob2, 0, 3);
    }
  }
}

// Round 5
// 1415.464 us; speedup vs baseline: 2.4157x; 1.0236x over previous
//
#include <hip/hip_runtime.h>
#include <math.h>

#define TB 256
#define SCAN_TOT 106250
#define SCAN_NB  104

static __device__ __forceinline__ int gtid() { return blockIdx.x * blockDim.x + threadIdx.x; }

static __device__ __forceinline__ void fma4(float4& a, float s, const float4 b) {
  a.x = fmaf(s, b.x, a.x); a.y = fmaf(s, b.y, a.y);
  a.z = fmaf(s, b.z, a.z); a.w = fmaf(s, b.w, a.w);
}

static __device__ __forceinline__ float bf_lo(unsigned u) {
  union { unsigned u; float f; } c; c.u = u << 16; return c.f;
}
static __device__ __forceinline__ float bf_hi(unsigned u) {
  union { unsigned u; float f; } c; c.u = u & 0xffff0000u; return c.f;
}
static __device__ __forceinline__ unsigned f2bf(float f) {
  union { float f; unsigned u; } c; c.f = f;
  return (c.u + 0x7fffu + ((c.u >> 16) & 1u)) >> 16;
}
static __device__ __forceinline__ unsigned pk2(float a, float b) {
  return f2bf(a) | (f2bf(b) << 16);
}

__global__ void fill_kernel(float* __restrict__ p, int n, float v) {
  int i = gtid(); if (i < n) p[i] = v;
}

__global__ void zero_int_kernel(int* __restrict__ p, int n) {
  int i = gtid(); if (i < n) p[i] = 0;
}

struct SegD {
  const int* rows[8];
  const int* cols[8];
  const float* vals[8];  // null => edge seg (compute sym-norm weight)
  int start[8];          // cumulative item starts
  int degb[8];           // base into deg/cursor/offs arrays
};

__global__ void count_all_kernel(SegD sg, int total, int* __restrict__ deg) {
  int t = gtid(); if (t >= total) return;
  int seg = 0;
  #pragma unroll
  for (int q = 1; q < 8; ++q) seg += (t >= sg.start[q]);
  int i = t - sg.start[seg];
  atomicAdd(&deg[sg.degb[seg] + sg.rows[seg][i]], 1);
}

__global__ void fill_all_kernel(SegD sg, int total, const int* __restrict__ deg,
                                const int* __restrict__ offs, int* __restrict__ cursor,
                                int* __restrict__ ccol, float* __restrict__ cwa) {
  int t = gtid(); if (t >= total) return;
  int seg = 0;
  #pragma unroll
  for (int q = 1; q < 8; ++q) seg += (t >= sg.start[q]);
  int i = t - sg.start[seg];
  int db = sg.degb[seg];
  int r = sg.rows[seg][i];
  int c = sg.cols[seg][i];
  int p = atomicAdd(&cursor[db + r], 1);
  int idx = offs[db + r] + p;
  float w;
  if (sg.vals[seg]) {
    w = sg.vals[seg][i];
  } else {
    int dc = deg[db + c];
    w = rsqrtf((float)deg[db + r]) * (dc > 0 ? rsqrtf((float)dc) : 0.f);
  }
  ccol[idx] = c;
  cwa[idx] = w;
}

// ---- 3-phase global exclusive scan over deg (SCAN_TOT elems, tiles of 1024) ----
__global__ void scan_phase1(const int* __restrict__ in, int* __restrict__ bsum) {
  __shared__ int wsum[4];
  int blk = blockIdx.x, t = threadIdx.x;
  int base = blk * 1024 + t * 4;
  int s = 0;
  #pragma unroll
  for (int q = 0; q < 4; ++q) { int i = base + q; if (i < SCAN_TOT) s += in[i]; }
  #pragma unroll
  for (int o = 32; o > 0; o >>= 1) s += __shfl_xor(s, o, 64);
  int lane = t & 63, wid = t >> 6;
  if (lane == 0) wsum[wid] = s;
  __syncthreads();
  if (t == 0) bsum[blk] = wsum[0] + wsum[1] + wsum[2] + wsum[3];
}

__global__ void scan_phase2(int* __restrict__ bsum, int* __restrict__ offs_end) {
  int t = threadIdx.x;  // 128
  int v = (t < SCAN_NB) ? bsum[t] : 0;
  int lane = t & 63, wid = t >> 6;
  int p = v;
  #pragma unroll
  for (int o = 1; o < 64; o <<= 1) { int u = __shfl_up(p, o, 64); if (lane >= o) p += u; }
  __shared__ int w0tot;
  if (wid == 0 && lane == 63) w0tot = p;
  __syncthreads();
  int incl = p + (wid ? w0tot : 0);
  if (t < SCAN_NB) bsum[t] = incl - v;
  if (t == 127) offs_end[0] = incl;
}

__global__ void scan_phase3(const int* __restrict__ in, const int* __restrict__ bbase,
                            int* __restrict__ offs, int* __restrict__ cursor) {
  __shared__ int wsum[4];
  int blk = blockIdx.x, t = threadIdx.x;
  int base = blk * 1024 + t * 4;
  int v[4]; int s = 0;
  #pragma unroll
  for (int q = 0; q < 4; ++q) { int i = base + q; v[q] = (i < SCAN_TOT) ? in[i] : 0; s += v[q]; }
  int lane = t & 63, wid = t >> 6;
  int p = s;
  #pragma unroll
  for (int o = 1; o < 64; o <<= 1) { int u = __shfl_up(p, o, 64); if (lane >= o) p += u; }
  if (lane == 63) wsum[wid] = p;
  __syncthreads();
  int woff = 0;
  #pragma unroll
  for (int q = 0; q < 4; ++q) woff += (q < wid) ? wsum[q] : 0;
  int ex = bbase[blk] + woff + p - s;
  #pragma unroll
  for (int q = 0; q < 4; ++q) {
    int i = base + q;
    if (i < SCAN_TOT) { offs[i] = ex; cursor[i] = 0; ex += v[q]; }
  }
}

// ---- fp32 pool (upper levels) ----
__global__ void pool_kernel(const float4* __restrict__ x, const int* __restrict__ offs,
                            const int* __restrict__ ccol, const float* __restrict__ cw,
                            float4* __restrict__ out, int n, int xs4, int xoff4,
                            int os4, int osh) {
  int t = gtid();
  if (t >= n * os4) return;
  int v = t >> osh, j = t & (os4 - 1);
  int s = offs[v], e = offs[v + 1];
  float4 a = {0.f, 0.f, 0.f, 0.f};
  for (int i = s; i < e; ++i)
    fma4(a, cw[i], x[(long long)ccol[i] * xs4 + xoff4 + j]);
  out[t] = a;
}

// ---- bf16 pool for level 0: H fp32 slice -> A bf16 [v][4bi][32ch] ----
__global__ void pool0_bf16_kernel(const float4* __restrict__ x, const int* __restrict__ offs,
                                  const int* __restrict__ ccol, const float* __restrict__ cw,
                                  uint4* __restrict__ out, int n, int xoff4) {
  int t = gtid();
  if (t >= n * 16) return;
  int v = t >> 4, j = t & 15;
  int s = offs[v], e = offs[v + 1];
  float4 a0 = {0.f, 0.f, 0.f, 0.f}, a1 = {0.f, 0.f, 0.f, 0.f};
  for (int i = s; i < e; ++i) {
    float w = cw[i];
    const float4* xr = x + (long long)ccol[i] * 128 + xoff4 + j * 2;
    fma4(a0, w, xr[0]); fma4(a1, w, xr[1]);
  }
  uint4 r;
  r.x = pk2(a0.x, a0.y); r.y = pk2(a0.z, a0.w);
  r.z = pk2(a1.x, a1.y); r.w = pk2(a1.z, a1.w);
  out[t] = r;
}

// ---- fp32 channel-split Clenshaw step (upper levels) ----
template<int CIN, int COUT>
__global__ void cheb_step_kernel(const float* __restrict__ X,
                                 const float* __restrict__ b1,
                                 float* __restrict__ b2o,
                                 const float* __restrict__ Wk,
                                 const float* __restrict__ bias,
                                 const int* __restrict__ offs,
                                 const int* __restrict__ ccol,
                                 const float* __restrict__ cw,
                                 int n, int LB, int mode) {
  constexpr int CS = COUT / 8;
  constexpr int LCS = (CS == 8) ? 3 : 2;
  constexpr int W4 = COUT / 4;
  __shared__ float sW[CIN * COUT];
  for (int i = threadIdx.x; i < CIN * COUT; i += blockDim.x) sW[i] = Wk[i];
  __syncthreads();
  int t = gtid();
  int BI = 1 << LB;
  if (t >= n * BI * CS) return;
  int cs = t & (CS - 1);
  int r = t >> LCS;
  int v = r >> LB;
  int bi = r & (BI - 1);
  float4 a0 = {0.f, 0.f, 0.f, 0.f}, a1 = {0.f, 0.f, 0.f, 0.f};
  const float4* Xr = (const float4*)(X + (long long)r * CIN);
  const float4* wbase = ((const float4*)sW) + cs * 2;
  #pragma unroll
  for (int c4 = 0; c4 < CIN / 4; ++c4) {
    float4 xv = Xr[c4];
    const float4* w = wbase + (c4 * 4) * W4;
    fma4(a0, xv.x, w[0]); fma4(a1, xv.x, w[1]); w += W4;
    fma4(a0, xv.y, w[0]); fma4(a1, xv.y, w[1]); w += W4;
    fma4(a0, xv.z, w[0]); fma4(a1, xv.z, w[1]); w += W4;
    fma4(a0, xv.w, w[0]); fma4(a1, xv.w, w[1]);
  }
  if (mode >= 1) {
    float sc = (mode == 3) ? 1.f : 2.f;
    int s = offs[v], e = offs[v + 1];
    const float4* b14 = (const float4*)b1;
    for (int i = s; i < e; ++i) {
      float w = cw[i] * sc;
      long long rb = (long long)((ccol[i] << LB) | bi) * W4 + cs * 2;
      fma4(a0, w, b14[rb]); fma4(a1, w, b14[rb + 1]);
    }
  }
  float4* Or = ((float4*)b2o) + (long long)r * W4 + cs * 2;
  if (mode >= 2) {
    float4 p0 = Or[0], p1 = Or[1];
    a0.x -= p0.x; a0.y -= p0.y; a0.z -= p0.z; a0.w -= p0.w;
    a1.x -= p1.x; a1.y -= p1.y; a1.z -= p1.z; a1.w -= p1.w;
  }
  if (mode == 3) {
    const float* bs = bias + cs * 8;
    a0.x += bs[0]; a0.y += bs[1]; a0.z += bs[2]; a0.w += bs[3];
    a1.x += bs[4]; a1.y += bs[5]; a1.z += bs[6]; a1.w += bs[7];
    a0.x = a0.x > 0.f ? a0.x : expm1f(a0.x);
    a0.y = a0.y > 0.f ? a0.y : expm1f(a0.y);
    a0.z = a0.z > 0.f ? a0.z : expm1f(a0.z);
    a0.w = a0.w > 0.f ? a0.w : expm1f(a0.w);
    a1.x = a1.x > 0.f ? a1.x : expm1f(a1.x);
    a1.y = a1.y > 0.f ? a1.y : expm1f(a1.y);
    a1.z = a1.z > 0.f ? a1.z : expm1f(a1.z);
    a1.w = a1.w > 0.f ? a1.w : expm1f(a1.w);
  }
  Or[0] = a0; Or[1] = a1;
}

// ---- bf16 Clenshaw step, level 0 only (CIN=COUT=32, BI=4) ----
__global__ void cheb0_bf16_kernel(const uint4* __restrict__ X,
                                  const uint4* __restrict__ b1,
                                  uint4* __restrict__ b2o,
                                  const float* __restrict__ Wk,
                                  const float* __restrict__ bias,
                                  const int* __restrict__ offs,
                                  const int* __restrict__ ccol,
                                  const float* __restrict__ cw,
                                  int n, int mode) {
  __shared__ float sW[1024];
  for (int i = threadIdx.x; i < 1024; i += blockDim.x) sW[i] = Wk[i];
  __syncthreads();
  int t = gtid();
  if (t >= n * 16) return;
  int cs = t & 3;
  int r = t >> 2;
  int v = r >> 2;
  int bi = r & 3;
  float4 a0 = {0.f, 0.f, 0.f, 0.f}, a1 = {0.f, 0.f, 0.f, 0.f};
  const uint4* Xr = X + (long long)r * 4;
  const float4* wbase = ((const float4*)sW) + cs * 2;
  #pragma unroll
  for (int q = 0; q < 4; ++q) {
    uint4 xv = Xr[q];
    const float4* w = wbase + (q * 8) * 8;
    float f;
    f = bf_lo(xv.x); fma4(a0, f, w[0]); fma4(a1, f, w[1]); w += 8;
    f = bf_hi(xv.x); fma4(a0, f, w[0]); fma4(a1, f, w[1]); w += 8;
    f = bf_lo(xv.y); fma4(a0, f, w[0]); fma4(a1, f, w[1]); w += 8;
    f = bf_hi(xv.y); fma4(a0, f, w[0]); fma4(a1, f, w[1]); w += 8;
    f = bf_lo(xv.z); fma4(a0, f, w[0]); fma4(a1, f, w[1]); w += 8;
    f = bf_hi(xv.z); fma4(a0, f, w[0]); fma4(a1, f, w[1]); w += 8;
    f = bf_lo(xv.w); fma4(a0, f, w[0]); fma4(a1, f, w[1]); w += 8;
    f = bf_hi(xv.w); fma4(a0, f, w[0]); fma4(a1, f, w[1]);
  }
  if (mode >= 1) {
    float sc = (mode == 3) ? 1.f : 2.f;
    int s = offs[v], e = offs[v + 1];
    for (int i = s; i < e; ++i) {
      float w = cw[i] * sc;
      uint4 bv = b1[(long long)((ccol[i] << 2) | bi) * 4 + cs];
      a0.x = fmaf(w, bf_lo(bv.x), a0.x); a0.y = fmaf(w, bf_hi(bv.x), a0.y);
      a0.z = fmaf(w, bf_lo(bv.y), a0.z); a0.w = fmaf(w, bf_hi(bv.y), a0.w);
      a1.x = fmaf(w, bf_lo(bv.z), a1.x); a1.y = fmaf(w, bf_hi(bv.z), a1.y);
      a1.z = fmaf(w, bf_lo(bv.w), a1.z); a1.w = fmaf(w, bf_hi(bv.w), a1.w);
    }
  }
  uint4* Or = b2o + (long long)r * 4 + cs;
  if (mode >= 2) {
    uint4 p = *Or;
    a0.x -= bf_lo(p.x); a0.y -= bf_hi(p.x);
    a0.z -= bf_lo(p.y); a0.w -= bf_hi(p.y);
    a1.x -= bf_lo(p.z); a1.y -= bf_hi(p.z);
    a1.z -= bf_lo(p.w); a1.w -= bf_hi(p.w);
  }
  if (mode == 3) {
    const float* bs = bias + cs * 8;
    a0.x += bs[0]; a0.y += bs[1]; a0.z += bs[2]; a0.w += bs[3];
    a1.x += bs[4]; a1.y += bs[5]; a1.z += bs[6]; a1.w += bs[7];
    a0.x = a0.x > 0.f ? a0.x : expm1f(a0.x);
    a0.y = a0.y > 0.f ? a0.y : expm1f(a0.y);
    a0.z = a0.z > 0.f ? a0.z : expm1f(a0.z);
    a0.w = a0.w > 0.f ? a0.w : expm1f(a0.w);
    a1.x = a1.x > 0.f ? a1.x : expm1f(a1.x);
    a1.y = a1.y > 0.f ? a1.y : expm1f(a1.y);
    a1.z = a1.z > 0.f ? a1.z : expm1f(a1.z);
    a1.w = a1.w > 0.f ? a1.w : expm1f(a1.w);
  }
  uint4 o;
  o.x = pk2(a0.x, a0.y); o.y = pk2(a0.z, a0.w);
  o.z = pk2(a1.x, a1.y); o.w = pk2(a1.z, a1.w);
  *Or = o;
}

// c_all[k][r][3] (bf16) = X[r]·Wout[k], X bf16 [r][32]
__global__ void gemm_out_all_kernel(const uint4* __restrict__ X, const float* __restrict__ W,
                                    unsigned short* __restrict__ c_all, int n4) {
  __shared__ float sW[576];
  for (int i = threadIdx.x; i < 576; i += blockDim.x) sW[i] = W[i];
  __syncthreads();
  int r = gtid();
  if (r >= n4) return;
  const uint4* Xr = X + (long long)r * 4;
  float xa[32];
  #pragma unroll
  for (int q = 0; q < 4; ++q) {
    uint4 xv = Xr[q];
    xa[q * 8 + 0] = bf_lo(xv.x); xa[q * 8 + 1] = bf_hi(xv.x);
    xa[q * 8 + 2] = bf_lo(xv.y); xa[q * 8 + 3] = bf_hi(xv.y);
    xa[q * 8 + 4] = bf_lo(xv.z); xa[q * 8 + 5] = bf_hi(xv.z);
    xa[q * 8 + 6] = bf_lo(xv.w); xa[q * 8 + 7] = bf_hi(xv.w);
  }
  float acc[18];
  #pragma unroll
  for (int i = 0; i < 18; ++i) acc[i] = 0.f;
  #pragma unroll
  for (int c = 0; c < 32; ++c) {
    float xc = xa[c];
    #pragma unroll
    for (int k = 0; k < 6; ++k) {
      acc[k * 3 + 0] = fmaf(xc, sW[k * 96 + c * 3 + 0], acc[k * 3 + 0]);
      acc[k * 3 + 1] = fmaf(xc, sW[k * 96 + c * 3 + 1], acc[k * 3 + 1]);
      acc[k * 3 + 2] = fmaf(xc, sW[k * 96 + c * 3 + 2], acc[k * 3 + 2]);
    }
  }
  #pragma unroll
  for (int k = 0; k < 6; ++k) {
    unsigned short* o = c_all + ((long long)k * n4 + r) * 3;
    o[0] = (unsigned short)f2bf(acc[k * 3 + 0]);
    o[1] = (unsigned short)f2bf(acc[k * 3 + 1]);
    o[2] = (unsigned short)f2bf(acc[k * 3 + 2]);
  }
}

// Clenshaw on tiny 3-ch buffers; c_all bf16 [k][r][3]; ob fp32; mode3 -> d_out
__global__ void cheb_out_step_kernel(const unsigned short* __restrict__ c_all, int k,
                                     const float* __restrict__ b1,
                                     float* __restrict__ b2o,
                                     const float* __restrict__ bias,
                                     const int* __restrict__ offs,
                                     const int* __restrict__ ccol,
                                     const float* __restrict__ cw,
                                     int n, float* __restrict__ dout, int mode) {
  int r = gtid();
  if (r >= n * 4) return;
  int v = r >> 2, bi = r & 3;
  const unsigned short* cr = c_all + ((long long)k * n * 4 + r) * 3;
  float a0 = bf_lo((unsigned)cr[0]), a1 = bf_lo((unsigned)cr[1]), a2 = bf_lo((unsigned)cr[2]);
  if (mode >= 1) {
    float sc = (mode == 3) ? 1.f : 2.f;
    int s = offs[v], e = offs[v + 1];
    for (int i = s; i < e; ++i) {
      float w = cw[i] * sc;
      const float* br = b1 + (long long)((ccol[i] << 2) | bi) * 3;
      a0 = fmaf(w, br[0], a0); a1 = fmaf(w, br[1], a1); a2 = fmaf(w, br[2], a2);
    }
  }
  if (mode >= 2) {
    const float* p = b2o + (long long)r * 3;
    a0 -= p[0]; a1 -= p[1]; a2 -= p[2];
  }
  if (mode == 3) {
    a0 += bias[0]; a1 += bias[1]; a2 += bias[2];
    float* o = dout + ((long long)bi * n + v) * 3;
    o[0] = a0; o[1] = a1; o[2] = a2;
  } else {
    float* o = b2o + (long long)r * 3;
    o[0] = a0; o[1] = a1; o[2] = a2;
  }
}

__global__ void linear_kernel(const float* __restrict__ x, const float* __restrict__ w,
                              const float* __restrict__ bias, float* __restrict__ out) {
  int t = gtid();
  const int TOT = 157 * 16 * 64;
  if (t >= TOT) return;
  int c = t & 63;
  int b = (t >> 6) & 15;
  int v = t >> 10;
  int colw = v * 64 + c;
  float acc = bias[colw];
  const float* xr = x + b * 128;
  for (int k = 0; k < 128; ++k) acc = fmaf(xr[k], w[k * 10048 + colw], acc);
  out[t] = acc;
}

extern "C" void kernel_launch(void* const* d_in, const int* in_sizes, int n_in,
                              void* d_out, int out_size, void* d_ws, size_t ws_size,
                              hipStream_t stream) {
  const int N[4] = {40000, 10000, 2500, 625};
  const int E[4] = {240000, 60000, 15000, 3750};
  const int NNZ[4] = {120000, 30000, 7500, 1875};
  const int DP[4] = {0, 40000, 50000, 52500};
  const int DE[4] = {53125, 93125, 103125, 105625};
  const int ITEMS = 478125;  // sum(NNZ) + sum(E)

  const float* x     = (const float*)d_in[0];
  const float* lin_w = (const float*)d_in[1];
  const float* lin_b = (const float*)d_in[2];
  const int* edge[4] = {(const int*)d_in[3], (const int*)d_in[4], (const int*)d_in[5], (const int*)d_in[6]};
  const int* up_row[4]; const int* up_col[4]; const float* up_val[4];
  for (int i = 0; i < 4; ++i) {
    up_row[i] = (const int*)d_in[7 + 3 * i];
    up_col[i] = (const int*)d_in[8 + 3 * i];
    up_val[i] = (const float*)d_in[9 + 3 * i];
  }
  const float* W_[5] = {(const float*)d_in[19], (const float*)d_in[21], (const float*)d_in[23],
                        (const float*)d_in[25], (const float*)d_in[27]};
  const float* b_[5] = {(const float*)d_in[20], (const float*)d_in[22], (const float*)d_in[24],
                        (const float*)d_in[26], (const float*)d_in[28]};

  char* ws = (char*)d_ws;
  size_t off = 0;
  auto alloc = [&](size_t bytes) -> void* {
    void* p = ws + off;
    off = (off + bytes + 255) & ~(size_t)255;
    return p;
  };
  auto cdiv = [](int a, int b) { return (a + b - 1) / b; };

  float* slot[4];
  for (int i = 0; i < 4; ++i) slot[i] = (float*)alloc(20480000ull);
  unsigned short* c_all = (unsigned short*)alloc((size_t)6 * 160000 * 3 * 2);
  float* ob1 = (float*)alloc((size_t)160000 * 3 * 4);
  float* ob2 = (float*)alloc((size_t)160000 * 3 * 4);
  int* deg_all    = (int*)alloc(SCAN_TOT * 4);
  int* cursor_all = (int*)alloc(SCAN_TOT * 4);
  int* offs_all   = (int*)alloc((SCAN_TOT + 1) * 4);
  int* bsum       = (int*)alloc(SCAN_NB * 4);
  int* col_arena  = (int*)alloc((size_t)ITEMS * 4);
  float* w_arena  = (float*)alloc((size_t)ITEMS * 4);

  if (off > ws_size) {
    fill_kernel<<<cdiv(out_size, TB), TB, 0, stream>>>((float*)d_out, out_size,
                                                       (float)(ws_size >> 20));
    return;
  }

  // ---- batched CSR build (6 launches) ----
  SegD sg;
  int cum = 0;
  for (int l = 0; l < 4; ++l) {
    sg.rows[l] = up_row[l]; sg.cols[l] = up_col[l]; sg.vals[l] = up_val[l];
    sg.start[l] = cum; sg.degb[l] = DP[l]; cum += NNZ[l];
  }
  for (int l = 0; l < 4; ++l) {
    sg.rows[4 + l] = edge[l]; sg.cols[4 + l] = edge[l] + E[l]; sg.vals[4 + l] = nullptr;
    sg.start[4 + l] = cum; sg.degb[4 + l] = DE[l]; cum += E[l];
  }
  zero_int_kernel<<<cdiv(SCAN_TOT, TB), TB, 0, stream>>>(deg_all, SCAN_TOT);
  count_all_kernel<<<cdiv(ITEMS, TB), TB, 0, stream>>>(sg, ITEMS, deg_all);
  scan_phase1<<<SCAN_NB, TB, 0, stream>>>(deg_all, bsum);
  scan_phase2<<<1, 128, 0, stream>>>(bsum, offs_all + SCAN_TOT);
  scan_phase3<<<SCAN_NB, TB, 0, stream>>>(deg_all, bsum, offs_all, cursor_all);
  fill_all_kernel<<<cdiv(ITEMS, TB), TB, 0, stream>>>(sg, ITEMS, deg_all, offs_all,
                                                      cursor_all, col_arena, w_arena);

  // latent -> h4 [157][16][64]
  linear_kernel<<<cdiv(157 * 16 * 64, TB), TB, 0, stream>>>(x, lin_w, lin_b, slot[0]);
  float* H = slot[0];
  float* A = slot[1];
  float* B = slot[2];
  float* C = slot[3];

  const int CINA[3]  = {64, 64, 32};
  const int COUTA[3] = {64, 32, 32};

  // ---- deblocks j=0..2 on meshes 3,2,1 (fp32, BI=16) ----
  for (int j = 0; j < 3; ++j) {
    int lvl = 3 - j;
    int n = N[lvl];
    int cin = CINA[j], cout = COUTA[j];
    int os4 = 16 * cin / 4;
    int osh = (os4 == 256) ? 8 : 7;
    const int* offs_p = offs_all + DP[lvl];
    const int* offs_e = offs_all + DE[lvl];

    pool_kernel<<<cdiv(n * os4, TB), TB, 0, stream>>>(
        (const float4*)H, offs_p, col_arena, w_arena, (float4*)A, n, os4, 0, os4, osh);

    int cs = cout / 8;
    dim3 g(cdiv(n * 16 * cs, TB));
    auto step = [&](const float* b1, float* b2o, int k, int mode) {
      const float* Wk = W_[j] + (size_t)k * cin * cout;
      if (cin == 64 && cout == 64)
        hipLaunchKernelGGL((cheb_step_kernel<64, 64>), g, dim3(TB), 0, stream,
                           A, b1, b2o, Wk, b_[j], offs_e, col_arena, w_arena, n, 4, mode);
      else if (cin == 64 && cout == 32)
        hipLaunchKernelGGL((cheb_step_kernel<64, 32>), g, dim3(TB), 0, stream,
                           A, b1, b2o, Wk, b_[j], offs_e, col_arena, w_arena, n, 4, mode);
      else
        hipLaunchKernelGGL((cheb_step_kernel<32, 32>), g, dim3(TB), 0, stream,
                           A, b1, b2o, Wk, b_[j], offs_e, col_arena, w_arena, n, 4, mode);
    };
    step(nullptr, B, 5, 0);
    step(B, C, 4, 1);
    step(C, B, 3, 2);
    step(B, C, 2, 2);
    step(C, B, 1, 2);
    step(B, C, 0, 3);

    float* tmp = H; H = C; C = tmp;
  }

  // ---- level 0: deblock j=3 + out conv, bf16 state, batch-split 4x4 ----
  {
    int n = N[0];
    int n4 = n * 4;
    const int* offs_p = offs_all + DP[0];
    const int* offs_e = offs_all + DE[0];
    dim3 g(cdiv(n * 16, TB));
    dim3 go(cdiv(n4, TB));
    uint4* Ab = (uint4*)A; uint4* Bb = (uint4*)B; uint4* Cb = (uint4*)C;
    for (int bg = 0; bg < 4; ++bg) {
      pool0_bf16_kernel<<<g, dim3(TB), 0, stream>>>(
          (const float4*)H, offs_p, col_arena, w_arena, Ab, n, bg * 32);
      auto dstep = [&](const uint4* b1, uint4* b2o, int k, int mode) {
        cheb0_bf16_kernel<<<g, dim3(TB), 0, stream>>>(
            Ab, b1, b2o, W_[3] + (size_t)k * 1024, b_[3],
            offs_e, col_arena, w_arena, n, mode);
      };
      dstep(nullptr, Bb, 5, 0);
      dstep(Bb, Cb, 4, 1);
      dstep(Cb, Bb, 3, 2);
      dstep(Bb, Cb, 2, 2);
      dstep(Cb, Bb, 1, 2);
      dstep(Bb, Cb, 0, 3);   // h0(bg) bf16 in Cb

      gemm_out_all_kernel<<<go, dim3(TB), 0, stream>>>(Cb, W_[4], c_all, n4);
      float* doutg = (float*)d_out + (size_t)bg * 4 * n * 3;
      auto ostep = [&](const float* b1, float* b2o, int k, int mode) {
        cheb_out_step_kernel<<<go, dim3(TB), 0, stream>>>(
            c_all, k, b1, b2o, b_[4], offs_e, col_arena, w_arena, n, doutg, mode);
      };
      ostep(nullptr, ob1, 5, 0);
      ostep(ob1, ob2, 4, 1);
      ostep(ob2, ob1, 3, 2);
      ostep(ob1, ob2, 2, 2);
      ostep(ob2, ob1, 1, 2);
      ostep(ob1, ob2, 0, 3);
    }
  }
}

// Round 6
// 1072.655 us; speedup vs baseline: 3.1877x; 1.3196x over previous
//
#include <hip/hip_runtime.h>
#include <math.h>

#define TB 256
#define SCAN_TOT 106250
#define SCAN_NB  104

static __device__ __forceinline__ int gtid() { return blockIdx.x * blockDim.x + threadIdx.x; }

static __device__ __forceinline__ void fma4(float4& a, float s, const float4 b) {
  a.x = fmaf(s, b.x, a.x); a.y = fmaf(s, b.y, a.y);
  a.z = fmaf(s, b.z, a.z); a.w = fmaf(s, b.w, a.w);
}

static __device__ __forceinline__ float bf_lo(unsigned u) {
  union { unsigned u; float f; } c; c.u = u << 16; return c.f;
}
static __device__ __forceinline__ float bf_hi(unsigned u) {
  union { unsigned u; float f; } c; c.u = u & 0xffff0000u; return c.f;
}
static __device__ __forceinline__ unsigned f2bf(float f) {
  union { float f; unsigned u; } c; c.f = f;
  return (c.u + 0x7fffu + ((c.u >> 16) & 1u)) >> 16;
}
static __device__ __forceinline__ unsigned pk2(float a, float b) {
  return f2bf(a) | (f2bf(b) << 16);
}

__global__ void fill_kernel(float* __restrict__ p, int n, float v) {
  int i = gtid(); if (i < n) p[i] = v;
}

__global__ void zero_int_kernel(int* __restrict__ p, int n) {
  int i = gtid(); if (i < n) p[i] = 0;
}

struct SegD {
  const int* rows[8];
  const int* cols[8];
  const float* vals[8];  // null => edge seg (compute sym-norm weight)
  int start[8];
  int degb[8];
};

__global__ void count_all_kernel(SegD sg, int total, int* __restrict__ deg) {
  int t = gtid(); if (t >= total) return;
  int seg = 0;
  #pragma unroll
  for (int q = 1; q < 8; ++q) seg += (t >= sg.start[q]);
  int i = t - sg.start[seg];
  atomicAdd(&deg[sg.degb[seg] + sg.rows[seg][i]], 1);
}

__global__ void fill_all_kernel(SegD sg, int total, const int* __restrict__ deg,
                                const int* __restrict__ offs, int* __restrict__ cursor,
                                int* __restrict__ ccol, float* __restrict__ cwa) {
  int t = gtid(); if (t >= total) return;
  int seg = 0;
  #pragma unroll
  for (int q = 1; q < 8; ++q) seg += (t >= sg.start[q]);
  int i = t - sg.start[seg];
  int db = sg.degb[seg];
  int r = sg.rows[seg][i];
  int c = sg.cols[seg][i];
  int p = atomicAdd(&cursor[db + r], 1);
  int idx = offs[db + r] + p;
  float w;
  if (sg.vals[seg]) {
    w = sg.vals[seg][i];
  } else {
    int dc = deg[db + c];
    w = rsqrtf((float)deg[db + r]) * (dc > 0 ? rsqrtf((float)dc) : 0.f);
  }
  ccol[idx] = c;
  cwa[idx] = w;
}

// ---- 3-phase global exclusive scan over deg ----
__global__ void scan_phase1(const int* __restrict__ in, int* __restrict__ bsum) {
  __shared__ int wsum[4];
  int blk = blockIdx.x, t = threadIdx.x;
  int base = blk * 1024 + t * 4;
  int s = 0;
  #pragma unroll
  for (int q = 0; q < 4; ++q) { int i = base + q; if (i < SCAN_TOT) s += in[i]; }
  #pragma unroll
  for (int o = 32; o > 0; o >>= 1) s += __shfl_xor(s, o, 64);
  int lane = t & 63, wid = t >> 6;
  if (lane == 0) wsum[wid] = s;
  __syncthreads();
  if (t == 0) bsum[blk] = wsum[0] + wsum[1] + wsum[2] + wsum[3];
}

__global__ void scan_phase2(int* __restrict__ bsum, int* __restrict__ offs_end) {
  int t = threadIdx.x;  // 128
  int v = (t < SCAN_NB) ? bsum[t] : 0;
  int lane = t & 63, wid = t >> 6;
  int p = v;
  #pragma unroll
  for (int o = 1; o < 64; o <<= 1) { int u = __shfl_up(p, o, 64); if (lane >= o) p += u; }
  __shared__ int w0tot;
  if (wid == 0 && lane == 63) w0tot = p;
  __syncthreads();
  int incl = p + (wid ? w0tot : 0);
  if (t < SCAN_NB) bsum[t] = incl - v;
  if (t == 127) offs_end[0] = incl;
}

__global__ void scan_phase3(const int* __restrict__ in, const int* __restrict__ bbase,
                            int* __restrict__ offs, int* __restrict__ cursor) {
  __shared__ int wsum[4];
  int blk = blockIdx.x, t = threadIdx.x;
  int base = blk * 1024 + t * 4;
  int v[4]; int s = 0;
  #pragma unroll
  for (int q = 0; q < 4; ++q) { int i = base + q; v[q] = (i < SCAN_TOT) ? in[i] : 0; s += v[q]; }
  int lane = t & 63, wid = t >> 6;
  int p = s;
  #pragma unroll
  for (int o = 1; o < 64; o <<= 1) { int u = __shfl_up(p, o, 64); if (lane >= o) p += u; }
  if (lane == 63) wsum[wid] = p;
  __syncthreads();
  int woff = 0;
  #pragma unroll
  for (int q = 0; q < 4; ++q) woff += (q < wid) ? wsum[q] : 0;
  int ex = bbase[blk] + woff + p - s;
  #pragma unroll
  for (int q = 0; q < 4; ++q) {
    int i = base + q;
    if (i < SCAN_TOT) { offs[i] = ex; cursor[i] = 0; ex += v[q]; }
  }
}

// ---- fp32 pool (upper levels) ----
__global__ void pool_kernel(const float4* __restrict__ x, const int* __restrict__ offs,
                            const int* __restrict__ ccol, const float* __restrict__ cw,
                            float4* __restrict__ out, int n, int xs4, int xoff4,
                            int os4, int osh) {
  int t = gtid();
  if (t >= n * os4) return;
  int v = t >> osh, j = t & (os4 - 1);
  int s = offs[v], e = offs[v + 1];
  float4 a = {0.f, 0.f, 0.f, 0.f};
  for (int i = s; i < e; ++i)
    fma4(a, cw[i], x[(long long)ccol[i] * xs4 + xoff4 + j]);
  out[t] = a;
}

// ---- bf16 pool for level 0, full batch: H fp32 [v][16bi][32ch] -> A bf16 same order ----
// thread t: v = t>>6, j = t&63 (j indexes 8-float group: bi=j>>2, ch8=j&3)
__global__ void pool0_bf16_kernel(const float4* __restrict__ x, const int* __restrict__ offs,
                                  const int* __restrict__ ccol, const float* __restrict__ cw,
                                  uint4* __restrict__ out, int n) {
  int t = gtid();
  if (t >= n * 64) return;
  int v = t >> 6, j = t & 63;
  int s = offs[v], e = offs[v + 1];
  float4 a0 = {0.f, 0.f, 0.f, 0.f}, a1 = {0.f, 0.f, 0.f, 0.f};
  for (int i = s; i < e; ++i) {
    float w = cw[i];
    const float4* xr = x + (long long)ccol[i] * 128 + j * 2;
    fma4(a0, w, xr[0]); fma4(a1, w, xr[1]);
  }
  uint4 r;
  r.x = pk2(a0.x, a0.y); r.y = pk2(a0.z, a0.w);
  r.z = pk2(a1.x, a1.y); r.w = pk2(a1.z, a1.w);
  out[t] = r;
}

// ---- fp32 channel-split Clenshaw step (upper levels) ----
template<int CIN, int COUT>
__global__ void cheb_step_kernel(const float* __restrict__ X,
                                 const float* __restrict__ b1,
                                 float* __restrict__ b2o,
                                 const float* __restrict__ Wk,
                                 const float* __restrict__ bias,
                                 const int* __restrict__ offs,
                                 const int* __restrict__ ccol,
                                 const float* __restrict__ cw,
                                 int n, int LB, int mode) {
  constexpr int CS = COUT / 8;
  constexpr int LCS = (CS == 8) ? 3 : 2;
  constexpr int W4 = COUT / 4;
  __shared__ float sW[CIN * COUT];
  for (int i = threadIdx.x; i < CIN * COUT; i += blockDim.x) sW[i] = Wk[i];
  __syncthreads();
  int t = gtid();
  int BI = 1 << LB;
  if (t >= n * BI * CS) return;
  int cs = t & (CS - 1);
  int r = t >> LCS;
  int v = r >> LB;
  int bi = r & (BI - 1);
  float4 a0 = {0.f, 0.f, 0.f, 0.f}, a1 = {0.f, 0.f, 0.f, 0.f};
  const float4* Xr = (const float4*)(X + (long long)r * CIN);
  const float4* wbase = ((const float4*)sW) + cs * 2;
  #pragma unroll
  for (int c4 = 0; c4 < CIN / 4; ++c4) {
    float4 xv = Xr[c4];
    const float4* w = wbase + (c4 * 4) * W4;
    fma4(a0, xv.x, w[0]); fma4(a1, xv.x, w[1]); w += W4;
    fma4(a0, xv.y, w[0]); fma4(a1, xv.y, w[1]); w += W4;
    fma4(a0, xv.z, w[0]); fma4(a1, xv.z, w[1]); w += W4;
    fma4(a0, xv.w, w[0]); fma4(a1, xv.w, w[1]);
  }
  if (mode >= 1) {
    float sc = (mode == 3) ? 1.f : 2.f;
    int s = offs[v], e = offs[v + 1];
    const float4* b14 = (const float4*)b1;
    for (int i = s; i < e; ++i) {
      float w = cw[i] * sc;
      long long rb = (long long)((ccol[i] << LB) | bi) * W4 + cs * 2;
      fma4(a0, w, b14[rb]); fma4(a1, w, b14[rb + 1]);
    }
  }
  float4* Or = ((float4*)b2o) + (long long)r * W4 + cs * 2;
  if (mode >= 2) {
    float4 p0 = Or[0], p1 = Or[1];
    a0.x -= p0.x; a0.y -= p0.y; a0.z -= p0.z; a0.w -= p0.w;
    a1.x -= p1.x; a1.y -= p1.y; a1.z -= p1.z; a1.w -= p1.w;
  }
  if (mode == 3) {
    const float* bs = bias + cs * 8;
    a0.x += bs[0]; a0.y += bs[1]; a0.z += bs[2]; a0.w += bs[3];
    a1.x += bs[4]; a1.y += bs[5]; a1.z += bs[6]; a1.w += bs[7];
    a0.x = a0.x > 0.f ? a0.x : expm1f(a0.x);
    a0.y = a0.y > 0.f ? a0.y : expm1f(a0.y);
    a0.z = a0.z > 0.f ? a0.z : expm1f(a0.z);
    a0.w = a0.w > 0.f ? a0.w : expm1f(a0.w);
    a1.x = a1.x > 0.f ? a1.x : expm1f(a1.x);
    a1.y = a1.y > 0.f ? a1.y : expm1f(a1.y);
    a1.z = a1.z > 0.f ? a1.z : expm1f(a1.z);
    a1.w = a1.w > 0.f ? a1.w : expm1f(a1.w);
  }
  Or[0] = a0; Or[1] = a1;
}

// ---- bf16 Clenshaw step, level 0, full batch (CIN=COUT=32, BI=16) ----
// thread t: cs = t&3, r = t>>2 (row = v*16+bi), v = r>>4, bi = r&15
__global__ void cheb0_bf16_kernel(const uint4* __restrict__ X,
                                  const uint4* __restrict__ b1,
                                  uint4* __restrict__ b2o,
                                  const float* __restrict__ Wk,
                                  const float* __restrict__ bias,
                                  const int* __restrict__ offs,
                                  const int* __restrict__ ccol,
                                  const float* __restrict__ cw,
                                  int n, int mode) {
  __shared__ float sW[1024];
  for (int i = threadIdx.x; i < 1024; i += blockDim.x) sW[i] = Wk[i];
  __syncthreads();
  int t = gtid();
  if (t >= n * 64) return;
  int cs = t & 3;
  int r = t >> 2;
  int v = r >> 4;
  int bi = r & 15;
  float4 a0 = {0.f, 0.f, 0.f, 0.f}, a1 = {0.f, 0.f, 0.f, 0.f};
  const uint4* Xr = X + (long long)r * 4;
  const float4* wbase = ((const float4*)sW) + cs * 2;
  #pragma unroll
  for (int q = 0; q < 4; ++q) {
    uint4 xv = Xr[q];
    const float4* w = wbase + (q * 8) * 8;
    float f;
    f = bf_lo(xv.x); fma4(a0, f, w[0]); fma4(a1, f, w[1]); w += 8;
    f = bf_hi(xv.x); fma4(a0, f, w[0]); fma4(a1, f, w[1]); w += 8;
    f = bf_lo(xv.y); fma4(a0, f, w[0]); fma4(a1, f, w[1]); w += 8;
    f = bf_hi(xv.y); fma4(a0, f, w[0]); fma4(a1, f, w[1]); w += 8;
    f = bf_lo(xv.z); fma4(a0, f, w[0]); fma4(a1, f, w[1]); w += 8;
    f = bf_hi(xv.z); fma4(a0, f, w[0]); fma4(a1, f, w[1]); w += 8;
    f = bf_lo(xv.w); fma4(a0, f, w[0]); fma4(a1, f, w[1]); w += 8;
    f = bf_hi(xv.w); fma4(a0, f, w[0]); fma4(a1, f, w[1]);
  }
  if (mode >= 1) {
    float sc = (mode == 3) ? 1.f : 2.f;
    int s = offs[v], e = offs[v + 1];
    for (int i = s; i < e; ++i) {
      float w = cw[i] * sc;
      uint4 bv = b1[(long long)((ccol[i] << 4) | bi) * 4 + cs];
      a0.x = fmaf(w, bf_lo(bv.x), a0.x); a0.y = fmaf(w, bf_hi(bv.x), a0.y);
      a0.z = fmaf(w, bf_lo(bv.y), a0.z); a0.w = fmaf(w, bf_hi(bv.y), a0.w);
      a1.x = fmaf(w, bf_lo(bv.z), a1.x); a1.y = fmaf(w, bf_hi(bv.z), a1.y);
      a1.z = fmaf(w, bf_lo(bv.w), a1.z); a1.w = fmaf(w, bf_hi(bv.w), a1.w);
    }
  }
  uint4* Or = b2o + (long long)r * 4 + cs;
  if (mode >= 2) {
    uint4 p = *Or;
    a0.x -= bf_lo(p.x); a0.y -= bf_hi(p.x);
    a0.z -= bf_lo(p.y); a0.w -= bf_hi(p.y);
    a1.x -= bf_lo(p.z); a1.y -= bf_hi(p.z);
    a1.z -= bf_lo(p.w); a1.w -= bf_hi(p.w);
  }
  if (mode == 3) {
    const float* bs = bias + cs * 8;
    a0.x += bs[0]; a0.y += bs[1]; a0.z += bs[2]; a0.w += bs[3];
    a1.x += bs[4]; a1.y += bs[5]; a1.z += bs[6]; a1.w += bs[7];
    a0.x = a0.x > 0.f ? a0.x : expm1f(a0.x);
    a0.y = a0.y > 0.f ? a0.y : expm1f(a0.y);
    a0.z = a0.z > 0.f ? a0.z : expm1f(a0.z);
    a0.w = a0.w > 0.f ? a0.w : expm1f(a0.w);
    a1.x = a1.x > 0.f ? a1.x : expm1f(a1.x);
    a1.y = a1.y > 0.f ? a1.y : expm1f(a1.y);
    a1.z = a1.z > 0.f ? a1.z : expm1f(a1.z);
    a1.w = a1.w > 0.f ? a1.w : expm1f(a1.w);
  }
  uint4 o;
  o.x = pk2(a0.x, a0.y); o.y = pk2(a0.z, a0.w);
  o.z = pk2(a1.x, a1.y); o.w = pk2(a1.z, a1.w);
  *Or = o;
}

// c_all[k][r][3] (bf16) = X[r]·Wout[k], X bf16 [r][32], r over n*16
__global__ void gemm_out_all_kernel(const uint4* __restrict__ X, const float* __restrict__ W,
                                    unsigned short* __restrict__ c_all, int nr) {
  __shared__ float sW[576];
  for (int i = threadIdx.x; i < 576; i += blockDim.x) sW[i] = W[i];
  __syncthreads();
  int r = gtid();
  if (r >= nr) return;
  const uint4* Xr = X + (long long)r * 4;
  float xa[32];
  #pragma unroll
  for (int q = 0; q < 4; ++q) {
    uint4 xv = Xr[q];
    xa[q * 8 + 0] = bf_lo(xv.x); xa[q * 8 + 1] = bf_hi(xv.x);
    xa[q * 8 + 2] = bf_lo(xv.y); xa[q * 8 + 3] = bf_hi(xv.y);
    xa[q * 8 + 4] = bf_lo(xv.z); xa[q * 8 + 5] = bf_hi(xv.z);
    xa[q * 8 + 6] = bf_lo(xv.w); xa[q * 8 + 7] = bf_hi(xv.w);
  }
  float acc[18];
  #pragma unroll
  for (int i = 0; i < 18; ++i) acc[i] = 0.f;
  #pragma unroll
  for (int c = 0; c < 32; ++c) {
    float xc = xa[c];
    #pragma unroll
    for (int k = 0; k < 6; ++k) {
      acc[k * 3 + 0] = fmaf(xc, sW[k * 96 + c * 3 + 0], acc[k * 3 + 0]);
      acc[k * 3 + 1] = fmaf(xc, sW[k * 96 + c * 3 + 1], acc[k * 3 + 1]);
      acc[k * 3 + 2] = fmaf(xc, sW[k * 96 + c * 3 + 2], acc[k * 3 + 2]);
    }
  }
  #pragma unroll
  for (int k = 0; k < 6; ++k) {
    unsigned short* o = c_all + ((long long)k * nr + r) * 3;
    o[0] = (unsigned short)f2bf(acc[k * 3 + 0]);
    o[1] = (unsigned short)f2bf(acc[k * 3 + 1]);
    o[2] = (unsigned short)f2bf(acc[k * 3 + 2]);
  }
}

// Clenshaw on tiny 3-ch buffers, full batch; r = v*16+bi; mode3 -> dout[(bi*n+v)*3]
__global__ void cheb_out_step_kernel(const unsigned short* __restrict__ c_all, int k,
                                     const float* __restrict__ b1,
                                     float* __restrict__ b2o,
                                     const float* __restrict__ bias,
                                     const int* __restrict__ offs,
                                     const int* __restrict__ ccol,
                                     const float* __restrict__ cw,
                                     int n, float* __restrict__ dout, int mode) {
  int r = gtid();
  if (r >= n * 16) return;
  int v = r >> 4, bi = r & 15;
  const unsigned short* cr = c_all + ((long long)k * n * 16 + r) * 3;
  float a0 = bf_lo((unsigned)cr[0]), a1 = bf_lo((unsigned)cr[1]), a2 = bf_lo((unsigned)cr[2]);
  if (mode >= 1) {
    float sc = (mode == 3) ? 1.f : 2.f;
    int s = offs[v], e = offs[v + 1];
    for (int i = s; i < e; ++i) {
      float w = cw[i] * sc;
      const float* br = b1 + (long long)((ccol[i] << 4) | bi) * 3;
      a0 = fmaf(w, br[0], a0); a1 = fmaf(w, br[1], a1); a2 = fmaf(w, br[2], a2);
    }
  }
  if (mode >= 2) {
    const float* p = b2o + (long long)r * 3;
    a0 -= p[0]; a1 -= p[1]; a2 -= p[2];
  }
  if (mode == 3) {
    a0 += bias[0]; a1 += bias[1]; a2 += bias[2];
    float* o = dout + ((long long)bi * n + v) * 3;
    o[0] = a0; o[1] = a1; o[2] = a2;
  } else {
    float* o = b2o + (long long)r * 3;
    o[0] = a0; o[1] = a1; o[2] = a2;
  }
}

__global__ void linear_kernel(const float* __restrict__ x, const float* __restrict__ w,
                              const float* __restrict__ bias, float* __restrict__ out) {
  int t = gtid();
  const int TOT = 157 * 16 * 64;
  if (t >= TOT) return;
  int c = t & 63;
  int b = (t >> 6) & 15;
  int v = t >> 10;
  int colw = v * 64 + c;
  float acc = bias[colw];
  const float* xr = x + b * 128;
  for (int k = 0; k < 128; ++k) acc = fmaf(xr[k], w[k * 10048 + colw], acc);
  out[t] = acc;
}

extern "C" void kernel_launch(void* const* d_in, const int* in_sizes, int n_in,
                              void* d_out, int out_size, void* d_ws, size_t ws_size,
                              hipStream_t stream) {
  const int N[4] = {40000, 10000, 2500, 625};
  const int E[4] = {240000, 60000, 15000, 3750};
  const int NNZ[4] = {120000, 30000, 7500, 1875};
  const int DP[4] = {0, 40000, 50000, 52500};
  const int DE[4] = {53125, 93125, 103125, 105625};
  const int ITEMS = 478125;

  const float* x     = (const float*)d_in[0];
  const float* lin_w = (const float*)d_in[1];
  const float* lin_b = (const float*)d_in[2];
  const int* edge[4] = {(const int*)d_in[3], (const int*)d_in[4], (const int*)d_in[5], (const int*)d_in[6]};
  const int* up_row[4]; const int* up_col[4]; const float* up_val[4];
  for (int i = 0; i < 4; ++i) {
    up_row[i] = (const int*)d_in[7 + 3 * i];
    up_col[i] = (const int*)d_in[8 + 3 * i];
    up_val[i] = (const float*)d_in[9 + 3 * i];
  }
  const float* W_[5] = {(const float*)d_in[19], (const float*)d_in[21], (const float*)d_in[23],
                        (const float*)d_in[25], (const float*)d_in[27]};
  const float* b_[5] = {(const float*)d_in[20], (const float*)d_in[22], (const float*)d_in[24],
                        (const float*)d_in[26], (const float*)d_in[28]};

  char* ws = (char*)d_ws;
  size_t off = 0;
  auto alloc = [&](size_t bytes) -> void* {
    void* p = ws + off;
    off = (off + bytes + 255) & ~(size_t)255;
    return p;
  };
  auto cdiv = [](int a, int b) { return (a + b - 1) / b; };

  float* slot[4];
  for (int i = 0; i < 4; ++i) slot[i] = (float*)alloc(20480000ull);  // upper-level fp32
  uint4* Ab = (uint4*)alloc(40960000ull);  // level-0 bf16 X   [40000][16][32]
  uint4* Bb = (uint4*)alloc(40960000ull);  // level-0 bf16 b
  uint4* Cb = (uint4*)alloc(40960000ull);  // level-0 bf16 b / h0
  unsigned short* c_all = (unsigned short*)alloc((size_t)6 * 640000 * 3 * 2);  // 23 MB
  float* ob1 = (float*)alloc((size_t)640000 * 3 * 4);
  float* ob2 = (float*)alloc((size_t)640000 * 3 * 4);
  int* deg_all    = (int*)alloc(SCAN_TOT * 4);
  int* cursor_all = (int*)alloc(SCAN_TOT * 4);
  int* offs_all   = (int*)alloc((SCAN_TOT + 1) * 4);
  int* bsum       = (int*)alloc(SCAN_NB * 4);
  int* col_arena  = (int*)alloc((size_t)ITEMS * 4);
  float* w_arena  = (float*)alloc((size_t)ITEMS * 4);

  if (off > ws_size) {
    fill_kernel<<<cdiv(out_size, TB), TB, 0, stream>>>((float*)d_out, out_size,
                                                       (float)(ws_size >> 20));
    return;
  }

  // ---- batched CSR build ----
  SegD sg;
  int cum = 0;
  for (int l = 0; l < 4; ++l) {
    sg.rows[l] = up_row[l]; sg.cols[l] = up_col[l]; sg.vals[l] = up_val[l];
    sg.start[l] = cum; sg.degb[l] = DP[l]; cum += NNZ[l];
  }
  for (int l = 0; l < 4; ++l) {
    sg.rows[4 + l] = edge[l]; sg.cols[4 + l] = edge[l] + E[l]; sg.vals[4 + l] = nullptr;
    sg.start[4 + l] = cum; sg.degb[4 + l] = DE[l]; cum += E[l];
  }
  zero_int_kernel<<<cdiv(SCAN_TOT, TB), TB, 0, stream>>>(deg_all, SCAN_TOT);
  count_all_kernel<<<cdiv(ITEMS, TB), TB, 0, stream>>>(sg, ITEMS, deg_all);
  scan_phase1<<<SCAN_NB, TB, 0, stream>>>(deg_all, bsum);
  scan_phase2<<<1, 128, 0, stream>>>(bsum, offs_all + SCAN_TOT);
  scan_phase3<<<SCAN_NB, TB, 0, stream>>>(deg_all, bsum, offs_all, cursor_all);
  fill_all_kernel<<<cdiv(ITEMS, TB), TB, 0, stream>>>(sg, ITEMS, deg_all, offs_all,
                                                      cursor_all, col_arena, w_arena);

  // latent -> h4 [157][16][64]
  linear_kernel<<<cdiv(157 * 16 * 64, TB), TB, 0, stream>>>(x, lin_w, lin_b, slot[0]);
  float* H = slot[0];
  float* A = slot[1];
  float* B = slot[2];
  float* C = slot[3];

  const int CINA[3]  = {64, 64, 32};
  const int COUTA[3] = {64, 32, 32};

  // ---- deblocks j=0..2 on meshes 3,2,1 (fp32, BI=16) ----
  for (int j = 0; j < 3; ++j) {
    int lvl = 3 - j;
    int n = N[lvl];
    int cin = CINA[j], cout = COUTA[j];
    int os4 = 16 * cin / 4;
    int osh = (os4 == 256) ? 8 : 7;
    const int* offs_p = offs_all + DP[lvl];
    const int* offs_e = offs_all + DE[lvl];

    pool_kernel<<<cdiv(n * os4, TB), TB, 0, stream>>>(
        (const float4*)H, offs_p, col_arena, w_arena, (float4*)A, n, os4, 0, os4, osh);

    int cs = cout / 8;
    dim3 g(cdiv(n * 16 * cs, TB));
    auto step = [&](const float* b1, float* b2o, int k, int mode) {
      const float* Wk = W_[j] + (size_t)k * cin * cout;
      if (cin == 64 && cout == 64)
        hipLaunchKernelGGL((cheb_step_kernel<64, 64>), g, dim3(TB), 0, stream,
                           A, b1, b2o, Wk, b_[j], offs_e, col_arena, w_arena, n, 4, mode);
      else if (cin == 64 && cout == 32)
        hipLaunchKernelGGL((cheb_step_kernel<64, 32>), g, dim3(TB), 0, stream,
                           A, b1, b2o, Wk, b_[j], offs_e, col_arena, w_arena, n, 4, mode);
      else
        hipLaunchKernelGGL((cheb_step_kernel<32, 32>), g, dim3(TB), 0, stream,
                           A, b1, b2o, Wk, b_[j], offs_e, col_arena, w_arena, n, 4, mode);
    };
    step(nullptr, B, 5, 0);
    step(B, C, 4, 1);
    step(C, B, 3, 2);
    step(B, C, 2, 2);
    step(C, B, 1, 2);
    step(B, C, 0, 3);

    float* tmp = H; H = C; C = tmp;
  }

  // ---- level 0: deblock j=3 + out conv, bf16 state, full batch ----
  {
    int n = N[0];
    int nr = n * 16;
    const int* offs_p = offs_all + DP[0];
    const int* offs_e = offs_all + DE[0];
    dim3 g64(cdiv(n * 64, TB));   // 10000 blocks
    dim3 gr(cdiv(nr, TB));        // 2500 blocks

    pool0_bf16_kernel<<<g64, dim3(TB), 0, stream>>>(
        (const float4*)H, offs_p, col_arena, w_arena, Ab, n);

    auto dstep = [&](const uint4* b1, uint4* b2o, int k, int mode) {
      cheb0_bf16_kernel<<<g64, dim3(TB), 0, stream>>>(
          Ab, b1, b2o, W_[3] + (size_t)k * 1024, b_[3],
          offs_e, col_arena, w_arena, n, mode);
    };
    dstep(nullptr, Bb, 5, 0);
    dstep(Bb, Cb, 4, 1);
    dstep(Cb, Bb, 3, 2);
    dstep(Bb, Cb, 2, 2);
    dstep(Cb, Bb, 1, 2);
    dstep(Bb, Cb, 0, 3);   // h0 bf16 in Cb

    gemm_out_all_kernel<<<gr, dim3(TB), 0, stream>>>(Cb, W_[4], c_all, nr);
    float* dout = (float*)d_out;
    auto ostep = [&](const float* b1, float* b2o, int k, int mode) {
      cheb_out_step_kernel<<<gr, dim3(TB), 0, stream>>>(
          c_all, k, b1, b2o, b_[4], offs_e, col_arena, w_arena, n, dout, mode);
    };
    ostep(nullptr, ob1, 5, 0);
    ostep(ob1, ob2, 4, 1);
    ostep(ob2, ob1, 3, 2);
    ostep(ob1, ob2, 2, 2);
    ostep(ob2, ob1, 1, 2);
    ostep(ob1, ob2, 0, 3);
  }
}

// Round 7
// 856.652 us; speedup vs baseline: 3.9915x; 1.2521x over previous
//
#include <hip/hip_runtime.h>
#include <math.h>

#define TB 256
#define SCAN_TOT 106250
#define SCAN_NB  104

typedef __bf16 bf16x8 __attribute__((ext_vector_type(8)));
typedef float f32x4 __attribute__((ext_vector_type(4)));

static __device__ __forceinline__ int gtid() { return blockIdx.x * blockDim.x + threadIdx.x; }

static __device__ __forceinline__ void fma4(float4& a, float s, const float4 b) {
  a.x = fmaf(s, b.x, a.x); a.y = fmaf(s, b.y, a.y);
  a.z = fmaf(s, b.z, a.z); a.w = fmaf(s, b.w, a.w);
}

static __device__ __forceinline__ float bf_lo(unsigned u) {
  union { unsigned u; float f; } c; c.u = u << 16; return c.f;
}
static __device__ __forceinline__ float bf_hi(unsigned u) {
  union { unsigned u; float f; } c; c.u = u & 0xffff0000u; return c.f;
}
static __device__ __forceinline__ float bfus(unsigned short u) {
  union { unsigned u; float f; } c; c.u = ((unsigned)u) << 16; return c.f;
}
static __device__ __forceinline__ unsigned f2bf(float f) {
  union { float f; unsigned u; } c; c.f = f;
  return (c.u + 0x7fffu + ((c.u >> 16) & 1u)) >> 16;
}
static __device__ __forceinline__ unsigned pk2(float a, float b) {
  return f2bf(a) | (f2bf(b) << 16);
}

__global__ void fill_kernel(float* __restrict__ p, int n, float v) {
  int i = gtid(); if (i < n) p[i] = v;
}

__global__ void zero_int_kernel(int* __restrict__ p, int n) {
  int i = gtid(); if (i < n) p[i] = 0;
}

struct SegD {
  const int* rows[8];
  const int* cols[8];
  const float* vals[8];  // null => edge seg (compute sym-norm weight)
  int start[8];
  int degb[8];
};

__global__ void count_all_kernel(SegD sg, int total, int* __restrict__ deg) {
  int t = gtid(); if (t >= total) return;
  int seg = 0;
  #pragma unroll
  for (int q = 1; q < 8; ++q) seg += (t >= sg.start[q]);
  int i = t - sg.start[seg];
  atomicAdd(&deg[sg.degb[seg] + sg.rows[seg][i]], 1);
}

__global__ void fill_all_kernel(SegD sg, int total, const int* __restrict__ deg,
                                const int* __restrict__ offs, int* __restrict__ cursor,
                                int* __restrict__ ccol, float* __restrict__ cwa) {
  int t = gtid(); if (t >= total) return;
  int seg = 0;
  #pragma unroll
  for (int q = 1; q < 8; ++q) seg += (t >= sg.start[q]);
  int i = t - sg.start[seg];
  int db = sg.degb[seg];
  int r = sg.rows[seg][i];
  int c = sg.cols[seg][i];
  int p = atomicAdd(&cursor[db + r], 1);
  int idx = offs[db + r] + p;
  float w;
  if (sg.vals[seg]) {
    w = sg.vals[seg][i];
  } else {
    int dc = deg[db + c];
    w = rsqrtf((float)deg[db + r]) * (dc > 0 ? rsqrtf((float)dc) : 0.f);
  }
  ccol[idx] = c;
  cwa[idx] = w;
}

// ---- 3-phase global exclusive scan over deg ----
__global__ void scan_phase1(const int* __restrict__ in, int* __restrict__ bsum) {
  __shared__ int wsum[4];
  int blk = blockIdx.x, t = threadIdx.x;
  int base = blk * 1024 + t * 4;
  int s = 0;
  #pragma unroll
  for (int q = 0; q < 4; ++q) { int i = base + q; if (i < SCAN_TOT) s += in[i]; }
  #pragma unroll
  for (int o = 32; o > 0; o >>= 1) s += __shfl_xor(s, o, 64);
  int lane = t & 63, wid = t >> 6;
  if (lane == 0) wsum[wid] = s;
  __syncthreads();
  if (t == 0) bsum[blk] = wsum[0] + wsum[1] + wsum[2] + wsum[3];
}

__global__ void scan_phase2(int* __restrict__ bsum, int* __restrict__ offs_end) {
  int t = threadIdx.x;  // 128
  int v = (t < SCAN_NB) ? bsum[t] : 0;
  int lane = t & 63, wid = t >> 6;
  int p = v;
  #pragma unroll
  for (int o = 1; o < 64; o <<= 1) { int u = __shfl_up(p, o, 64); if (lane >= o) p += u; }
  __shared__ int w0tot;
  if (wid == 0 && lane == 63) w0tot = p;
  __syncthreads();
  int incl = p + (wid ? w0tot : 0);
  if (t < SCAN_NB) bsum[t] = incl - v;
  if (t == 127) offs_end[0] = incl;
}

__global__ void scan_phase3(const int* __restrict__ in, const int* __restrict__ bbase,
                            int* __restrict__ offs, int* __restrict__ cursor) {
  __shared__ int wsum[4];
  int blk = blockIdx.x, t = threadIdx.x;
  int base = blk * 1024 + t * 4;
  int v[4]; int s = 0;
  #pragma unroll
  for (int q = 0; q < 4; ++q) { int i = base + q; v[q] = (i < SCAN_TOT) ? in[i] : 0; s += v[q]; }
  int lane = t & 63, wid = t >> 6;
  int p = s;
  #pragma unroll
  for (int o = 1; o < 64; o <<= 1) { int u = __shfl_up(p, o, 64); if (lane >= o) p += u; }
  if (lane == 63) wsum[wid] = p;
  __syncthreads();
  int woff = 0;
  #pragma unroll
  for (int q = 0; q < 4; ++q) woff += (q < wid) ? wsum[q] : 0;
  int ex = bbase[blk] + woff + p - s;
  #pragma unroll
  for (int q = 0; q < 4; ++q) {
    int i = base + q;
    if (i < SCAN_TOT) { offs[i] = ex; cursor[i] = 0; ex += v[q]; }
  }
}

// ---- fp32 pool (upper levels) ----
__global__ void pool_kernel(const float4* __restrict__ x, const int* __restrict__ offs,
                            const int* __restrict__ ccol, const float* __restrict__ cw,
                            float4* __restrict__ out, int n, int xs4, int xoff4,
                            int os4, int osh) {
  int t = gtid();
  if (t >= n * os4) return;
  int v = t >> osh, j = t & (os4 - 1);
  int s = offs[v], e = offs[v + 1];
  float4 a = {0.f, 0.f, 0.f, 0.f};
  for (int i = s; i < e; ++i)
    fma4(a, cw[i], x[(long long)ccol[i] * xs4 + xoff4 + j]);
  out[t] = a;
}

// ---- bf16 pool for level 0, full batch: H fp32 [v][16bi][32ch] -> A bf16 same order ----
__global__ void pool0_bf16_kernel(const float4* __restrict__ x, const int* __restrict__ offs,
                                  const int* __restrict__ ccol, const float* __restrict__ cw,
                                  uint4* __restrict__ out, int n) {
  int t = gtid();
  if (t >= n * 64) return;
  int v = t >> 6, j = t & 63;
  int s = offs[v], e = offs[v + 1];
  float4 a0 = {0.f, 0.f, 0.f, 0.f}, a1 = {0.f, 0.f, 0.f, 0.f};
  for (int i = s; i < e; ++i) {
    float w = cw[i];
    const float4* xr = x + (long long)ccol[i] * 128 + j * 2;
    fma4(a0, w, xr[0]); fma4(a1, w, xr[1]);
  }
  uint4 r;
  r.x = pk2(a0.x, a0.y); r.y = pk2(a0.z, a0.w);
  r.z = pk2(a1.x, a1.y); r.w = pk2(a1.z, a1.w);
  out[t] = r;
}

// ---- fp32 channel-split Clenshaw step (upper levels) ----
template<int CIN, int COUT>
__global__ void cheb_step_kernel(const float* __restrict__ X,
                                 const float* __restrict__ b1,
                                 float* __restrict__ b2o,
                                 const float* __restrict__ Wk,
                                 const float* __restrict__ bias,
                                 const int* __restrict__ offs,
                                 const int* __restrict__ ccol,
                                 const float* __restrict__ cw,
                                 int n, int LB, int mode) {
  constexpr int CS = COUT / 8;
  constexpr int LCS = (CS == 8) ? 3 : 2;
  constexpr int W4 = COUT / 4;
  __shared__ float sW[CIN * COUT];
  for (int i = threadIdx.x; i < CIN * COUT; i += blockDim.x) sW[i] = Wk[i];
  __syncthreads();
  int t = gtid();
  int BI = 1 << LB;
  if (t >= n * BI * CS) return;
  int cs = t & (CS - 1);
  int r = t >> LCS;
  int v = r >> LB;
  int bi = r & (BI - 1);
  float4 a0 = {0.f, 0.f, 0.f, 0.f}, a1 = {0.f, 0.f, 0.f, 0.f};
  const float4* Xr = (const float4*)(X + (long long)r * CIN);
  const float4* wbase = ((const float4*)sW) + cs * 2;
  #pragma unroll
  for (int c4 = 0; c4 < CIN / 4; ++c4) {
    float4 xv = Xr[c4];
    const float4* w = wbase + (c4 * 4) * W4;
    fma4(a0, xv.x, w[0]); fma4(a1, xv.x, w[1]); w += W4;
    fma4(a0, xv.y, w[0]); fma4(a1, xv.y, w[1]); w += W4;
    fma4(a0, xv.z, w[0]); fma4(a1, xv.z, w[1]); w += W4;
    fma4(a0, xv.w, w[0]); fma4(a1, xv.w, w[1]);
  }
  if (mode >= 1) {
    float sc = (mode == 3) ? 1.f : 2.f;
    int s = offs[v], e = offs[v + 1];
    const float4* b14 = (const float4*)b1;
    for (int i = s; i < e; ++i) {
      float w = cw[i] * sc;
      long long rb = (long long)((ccol[i] << LB) | bi) * W4 + cs * 2;
      fma4(a0, w, b14[rb]); fma4(a1, w, b14[rb + 1]);
    }
  }
  float4* Or = ((float4*)b2o) + (long long)r * W4 + cs * 2;
  if (mode >= 2) {
    float4 p0 = Or[0], p1 = Or[1];
    a0.x -= p0.x; a0.y -= p0.y; a0.z -= p0.z; a0.w -= p0.w;
    a1.x -= p1.x; a1.y -= p1.y; a1.z -= p1.z; a1.w -= p1.w;
  }
  if (mode == 3) {
    const float* bs = bias + cs * 8;
    a0.x += bs[0]; a0.y += bs[1]; a0.z += bs[2]; a0.w += bs[3];
    a1.x += bs[4]; a1.y += bs[5]; a1.z += bs[6]; a1.w += bs[7];
    a0.x = a0.x > 0.f ? a0.x : expm1f(a0.x);
    a0.y = a0.y > 0.f ? a0.y : expm1f(a0.y);
    a0.z = a0.z > 0.f ? a0.z : expm1f(a0.z);
    a0.w = a0.w > 0.f ? a0.w : expm1f(a0.w);
    a1.x = a1.x > 0.f ? a1.x : expm1f(a1.x);
    a1.y = a1.y > 0.f ? a1.y : expm1f(a1.y);
    a1.z = a1.z > 0.f ? a1.z : expm1f(a1.z);
    a1.w = a1.w > 0.f ? a1.w : expm1f(a1.w);
  }
  Or[0] = a0; Or[1] = a1;
}

// ---- MFMA Clenshaw step, level 0 (CIN=COUT=32, BI=16): one wave per vertex ----
// A-frag: X[v*16 + (lane&15)][8*(lane>>4) .. +8)   (one uint4 load)
// B-frags: W_k col (lane&15) / (lane&15)+16, k = 8*(lane>>4)+j  (held in VGPRs)
// D: rows 4*(lane>>4)+q, cols lane&15 and (lane&15)+16
__global__ void __launch_bounds__(256)
cheb0_mfma_kernel(const uint4* __restrict__ X,
                  const unsigned short* __restrict__ b1,
                  unsigned short* __restrict__ b2o,
                  const float* __restrict__ Wk,
                  const float* __restrict__ bias,
                  const int* __restrict__ offs,
                  const int* __restrict__ ccol,
                  const float* __restrict__ cw,
                  int n, int mode) {
  int lane = threadIdx.x & 63;
  int v = (blockIdx.x << 2) | (threadIdx.x >> 6);
  if (v >= n) return;
  int g = lane >> 4;
  int c15 = lane & 15;

  union { uint4 u; bf16x8 v; } Au;
  Au.u = X[((long long)(v * 16 + c15)) * 4 + g];

  bf16x8 B0, B1;
  #pragma unroll
  for (int j = 0; j < 8; ++j) {
    int k = 8 * g + j;
    B0[j] = (__bf16)Wk[k * 32 + c15];
    B1[j] = (__bf16)Wk[k * 32 + 16 + c15];
  }
  f32x4 z = {0.f, 0.f, 0.f, 0.f};
  f32x4 acc0 = __builtin_amdgcn_mfma_f32_16x16x32_bf16(Au.v, B0, z, 0, 0, 0);
  f32x4 acc1 = __builtin_amdgcn_mfma_f32_16x16x32_bf16(Au.v, B1, z, 0, 0, 0);

  if (mode >= 1) {
    float sc = (mode == 3) ? 1.f : 2.f;
    int s = offs[v], e = offs[v + 1];
    for (int i = s; i < e; ++i) {
      float w = cw[i] * sc;
      long long base = ((long long)ccol[i] * 16 + 4 * g) * 32;
      #pragma unroll
      for (int q = 0; q < 4; ++q) {
        acc0[q] = fmaf(w, bfus(b1[base + q * 32 + c15]), acc0[q]);
        acc1[q] = fmaf(w, bfus(b1[base + q * 32 + 16 + c15]), acc1[q]);
      }
    }
  }
  long long rb = ((long long)v * 16 + 4 * g) * 32;
  if (mode >= 2) {
    #pragma unroll
    for (int q = 0; q < 4; ++q) {
      acc0[q] -= bfus(b2o[rb + q * 32 + c15]);
      acc1[q] -= bfus(b2o[rb + q * 32 + 16 + c15]);
    }
  }
  if (mode == 3) {
    float bs0 = bias[c15], bs1 = bias[16 + c15];
    #pragma unroll
    for (int q = 0; q < 4; ++q) {
      float a = acc0[q] + bs0;
      float b = acc1[q] + bs1;
      acc0[q] = a > 0.f ? a : expm1f(a);
      acc1[q] = b > 0.f ? b : expm1f(b);
    }
  }
  #pragma unroll
  for (int q = 0; q < 4; ++q) {
    b2o[rb + q * 32 + c15] = (unsigned short)f2bf(acc0[q]);
    b2o[rb + q * 32 + 16 + c15] = (unsigned short)f2bf(acc1[q]);
  }
}

// c_all[k][r][3] (bf16) = X[r]·Wout[k], X bf16 [r][32], r over n*16
__global__ void gemm_out_all_kernel(const uint4* __restrict__ X, const float* __restrict__ W,
                                    unsigned short* __restrict__ c_all, int nr) {
  __shared__ float sW[576];
  for (int i = threadIdx.x; i < 576; i += blockDim.x) sW[i] = W[i];
  __syncthreads();
  int r = gtid();
  if (r >= nr) return;
  const uint4* Xr = X + (long long)r * 4;
  float xa[32];
  #pragma unroll
  for (int q = 0; q < 4; ++q) {
    uint4 xv = Xr[q];
    xa[q * 8 + 0] = bf_lo(xv.x); xa[q * 8 + 1] = bf_hi(xv.x);
    xa[q * 8 + 2] = bf_lo(xv.y); xa[q * 8 + 3] = bf_hi(xv.y);
    xa[q * 8 + 4] = bf_lo(xv.z); xa[q * 8 + 5] = bf_hi(xv.z);
    xa[q * 8 + 6] = bf_lo(xv.w); xa[q * 8 + 7] = bf_hi(xv.w);
  }
  float acc[18];
  #pragma unroll
  for (int i = 0; i < 18; ++i) acc[i] = 0.f;
  #pragma unroll
  for (int c = 0; c < 32; ++c) {
    float xc = xa[c];
    #pragma unroll
    for (int k = 0; k < 6; ++k) {
      acc[k * 3 + 0] = fmaf(xc, sW[k * 96 + c * 3 + 0], acc[k * 3 + 0]);
      acc[k * 3 + 1] = fmaf(xc, sW[k * 96 + c * 3 + 1], acc[k * 3 + 1]);
      acc[k * 3 + 2] = fmaf(xc, sW[k * 96 + c * 3 + 2], acc[k * 3 + 2]);
    }
  }
  #pragma unroll
  for (int k = 0; k < 6; ++k) {
    unsigned short* o = c_all + ((long long)k * nr + r) * 3;
    o[0] = (unsigned short)f2bf(acc[k * 3 + 0]);
    o[1] = (unsigned short)f2bf(acc[k * 3 + 1]);
    o[2] = (unsigned short)f2bf(acc[k * 3 + 2]);
  }
}

// Clenshaw on tiny 3-ch buffers, full batch; r = v*16+bi; mode3 -> dout[(bi*n+v)*3]
__global__ void cheb_out_step_kernel(const unsigned short* __restrict__ c_all, int k,
                                     const float* __restrict__ b1,
                                     float* __restrict__ b2o,
                                     const float* __restrict__ bias,
                                     const int* __restrict__ offs,
                                     const int* __restrict__ ccol,
                                     const float* __restrict__ cw,
                                     int n, float* __restrict__ dout, int mode) {
  int r = gtid();
  if (r >= n * 16) return;
  int v = r >> 4, bi = r & 15;
  const unsigned short* cr = c_all + ((long long)k * n * 16 + r) * 3;
  float a0 = bfus(cr[0]), a1 = bfus(cr[1]), a2 = bfus(cr[2]);
  if (mode >= 1) {
    float sc = (mode == 3) ? 1.f : 2.f;
    int s = offs[v], e = offs[v + 1];
    for (int i = s; i < e; ++i) {
      float w = cw[i] * sc;
      const float* br = b1 + (long long)((ccol[i] << 4) | bi) * 3;
      a0 = fmaf(w, br[0], a0); a1 = fmaf(w, br[1], a1); a2 = fmaf(w, br[2], a2);
    }
  }
  if (mode >= 2) {
    const float* p = b2o + (long long)r * 3;
    a0 -= p[0]; a1 -= p[1]; a2 -= p[2];
  }
  if (mode == 3) {
    a0 += bias[0]; a1 += bias[1]; a2 += bias[2];
    float* o = dout + ((long long)bi * n + v) * 3;
    o[0] = a0; o[1] = a1; o[2] = a2;
  } else {
    float* o = b2o + (long long)r * 3;
    o[0] = a0; o[1] = a1; o[2] = a2;
  }
}

__global__ void linear_kernel(const float* __restrict__ x, const float* __restrict__ w,
                              const float* __restrict__ bias, float* __restrict__ out) {
  int t = gtid();
  const int TOT = 157 * 16 * 64;
  if (t >= TOT) return;
  int c = t & 63;
  int b = (t >> 6) & 15;
  int v = t >> 10;
  int colw = v * 64 + c;
  float acc = bias[colw];
  const float* xr = x + b * 128;
  for (int k = 0; k < 128; ++k) acc = fmaf(xr[k], w[k * 10048 + colw], acc);
  out[t] = acc;
}

extern "C" void kernel_launch(void* const* d_in, const int* in_sizes, int n_in,
                              void* d_out, int out_size, void* d_ws, size_t ws_size,
                              hipStream_t stream) {
  const int N[4] = {40000, 10000, 2500, 625};
  const int E[4] = {240000, 60000, 15000, 3750};
  const int NNZ[4] = {120000, 30000, 7500, 1875};
  const int DP[4] = {0, 40000, 50000, 52500};
  const int DE[4] = {53125, 93125, 103125, 105625};
  const int ITEMS = 478125;

  const float* x     = (const float*)d_in[0];
  const float* lin_w = (const float*)d_in[1];
  const float* lin_b = (const float*)d_in[2];
  const int* edge[4] = {(const int*)d_in[3], (const int*)d_in[4], (const int*)d_in[5], (const int*)d_in[6]};
  const int* up_row[4]; const int* up_col[4]; const float* up_val[4];
  for (int i = 0; i < 4; ++i) {
    up_row[i] = (const int*)d_in[7 + 3 * i];
    up_col[i] = (const int*)d_in[8 + 3 * i];
    up_val[i] = (const float*)d_in[9 + 3 * i];
  }
  const float* W_[5] = {(const float*)d_in[19], (const float*)d_in[21], (const float*)d_in[23],
                        (const float*)d_in[25], (const float*)d_in[27]};
  const float* b_[5] = {(const float*)d_in[20], (const float*)d_in[22], (const float*)d_in[24],
                        (const float*)d_in[26], (const float*)d_in[28]};

  char* ws = (char*)d_ws;
  size_t off = 0;
  auto alloc = [&](size_t bytes) -> void* {
    void* p = ws + off;
    off = (off + bytes + 255) & ~(size_t)255;
    return p;
  };
  auto cdiv = [](int a, int b) { return (a + b - 1) / b; };

  float* slot[4];
  for (int i = 0; i < 4; ++i) slot[i] = (float*)alloc(20480000ull);  // upper-level fp32
  uint4* Ab = (uint4*)alloc(40960000ull);  // level-0 bf16 X   [40000][16][32]
  uint4* Bb = (uint4*)alloc(40960000ull);  // level-0 bf16 b
  uint4* Cb = (uint4*)alloc(40960000ull);  // level-0 bf16 b / h0
  unsigned short* c_all = (unsigned short*)alloc((size_t)6 * 640000 * 3 * 2);  // 23 MB
  float* ob1 = (float*)alloc((size_t)640000 * 3 * 4);
  float* ob2 = (float*)alloc((size_t)640000 * 3 * 4);
  int* deg_all    = (int*)alloc(SCAN_TOT * 4);
  int* cursor_all = (int*)alloc(SCAN_TOT * 4);
  int* offs_all   = (int*)alloc((SCAN_TOT + 1) * 4);
  int* bsum       = (int*)alloc(SCAN_NB * 4);
  int* col_arena  = (int*)alloc((size_t)ITEMS * 4);
  float* w_arena  = (float*)alloc((size_t)ITEMS * 4);

  if (off > ws_size) {
    fill_kernel<<<cdiv(out_size, TB), TB, 0, stream>>>((float*)d_out, out_size,
                                                       (float)(ws_size >> 20));
    return;
  }

  // ---- batched CSR build ----
  SegD sg;
  int cum = 0;
  for (int l = 0; l < 4; ++l) {
    sg.rows[l] = up_row[l]; sg.cols[l] = up_col[l]; sg.vals[l] = up_val[l];
    sg.start[l] = cum; sg.degb[l] = DP[l]; cum += NNZ[l];
  }
  for (int l = 0; l < 4; ++l) {
    sg.rows[4 + l] = edge[l]; sg.cols[4 + l] = edge[l] + E[l]; sg.vals[4 + l] = nullptr;
    sg.start[4 + l] = cum; sg.degb[4 + l] = DE[l]; cum += E[l];
  }
  zero_int_kernel<<<cdiv(SCAN_TOT, TB), TB, 0, stream>>>(deg_all, SCAN_TOT);
  count_all_kernel<<<cdiv(ITEMS, TB), TB, 0, stream>>>(sg, ITEMS, deg_all);
  scan_phase1<<<SCAN_NB, TB, 0, stream>>>(deg_all, bsum);
  scan_phase2<<<1, 128, 0, stream>>>(bsum, offs_all + SCAN_TOT);
  scan_phase3<<<SCAN_NB, TB, 0, stream>>>(deg_all, bsum, offs_all, cursor_all);
  fill_all_kernel<<<cdiv(ITEMS, TB), TB, 0, stream>>>(sg, ITEMS, deg_all, offs_all,
                                                      cursor_all, col_arena, w_arena);

  // latent -> h4 [157][16][64]
  linear_kernel<<<cdiv(157 * 16 * 64, TB), TB, 0, stream>>>(x, lin_w, lin_b, slot[0]);
  float* H = slot[0];
  float* A = slot[1];
  float* B = slot[2];
  float* C = slot[3];

  const int CINA[3]  = {64, 64, 32};
  const int COUTA[3] = {64, 32, 32};

  // ---- deblocks j=0..2 on meshes 3,2,1 (fp32, BI=16) ----
  for (int j = 0; j < 3; ++j) {
    int lvl = 3 - j;
    int n = N[lvl];
    int cin = CINA[j], cout = COUTA[j];
    int os4 = 16 * cin / 4;
    int osh = (os4 == 256) ? 8 : 7;
    const int* offs_p = offs_all + DP[lvl];
    const int* offs_e = offs_all + DE[lvl];

    pool_kernel<<<cdiv(n * os4, TB), TB, 0, stream>>>(
        (const float4*)H, offs_p, col_arena, w_arena, (float4*)A, n, os4, 0, os4, osh);

    int cs = cout / 8;
    dim3 g(cdiv(n * 16 * cs, TB));
    auto step = [&](const float* b1, float* b2o, int k, int mode) {
      const float* Wk = W_[j] + (size_t)k * cin * cout;
      if (cin == 64 && cout == 64)
        hipLaunchKernelGGL((cheb_step_kernel<64, 64>), g, dim3(TB), 0, stream,
                           A, b1, b2o, Wk, b_[j], offs_e, col_arena, w_arena, n, 4, mode);
      else if (cin == 64 && cout == 32)
        hipLaunchKernelGGL((cheb_step_kernel<64, 32>), g, dim3(TB), 0, stream,
                           A, b1, b2o, Wk, b_[j], offs_e, col_arena, w_arena, n, 4, mode);
      else
        hipLaunchKernelGGL((cheb_step_kernel<32, 32>), g, dim3(TB), 0, stream,
                           A, b1, b2o, Wk, b_[j], offs_e, col_arena, w_arena, n, 4, mode);
    };
    step(nullptr, B, 5, 0);
    step(B, C, 4, 1);
    step(C, B, 3, 2);
    step(B, C, 2, 2);
    step(C, B, 1, 2);
    step(B, C, 0, 3);

    float* tmp = H; H = C; C = tmp;
  }

  // ---- level 0: deblock j=3 via MFMA (one wave per vertex) + out conv ----
  {
    int n = N[0];
    int nr = n * 16;
    const int* offs_p = offs_all + DP[0];
    const int* offs_e = offs_all + DE[0];
    dim3 g64(cdiv(n * 64, TB));   // pool: 10000 blocks
    dim3 gmf(n / 4);              // mfma: 4 vertices (waves) per block
    dim3 gr(cdiv(nr, TB));

    pool0_bf16_kernel<<<g64, dim3(TB), 0, stream>>>(
        (const float4*)H, offs_p, col_arena, w_arena, Ab, n);

    auto dstep = [&](const uint4* b1, uint4* b2o, int k, int mode) {
      cheb0_mfma_kernel<<<gmf, dim3(TB), 0, stream>>>(
          Ab, (const unsigned short*)b1, (unsigned short*)b2o,
          W_[3] + (size_t)k * 1024, b_[3],
          offs_e, col_arena, w_arena, n, mode);
    };
    dstep(nullptr, Bb, 5, 0);
    dstep(Bb, Cb, 4, 1);
    dstep(Cb, Bb, 3, 2);
    dstep(Bb, Cb, 2, 2);
    dstep(Cb, Bb, 1, 2);
    dstep(Bb, Cb, 0, 3);   // h0 bf16 in Cb

    gemm_out_all_kernel<<<gr, dim3(TB), 0, stream>>>(Cb, W_[4], c_all, nr);
    float* dout = (float*)d_out;
    auto ostep = [&](const float* b1, float* b2o, int k, int mode) {
      cheb_out_step_kernel<<<gr, dim3(TB), 0, stream>>>(
          c_all, k, b1, b2o, b_[4], offs_e, col_arena, w_arena, n, dout, mode);
    };
    ostep(nullptr, ob1, 5, 0);
    ostep(ob1, ob2, 4, 1);
    ostep(ob2, ob1, 3, 2);
    ostep(ob1, ob2, 2, 2);
    ostep(ob2, ob1, 1, 2);
    ostep(ob1, ob2, 0, 3);
  }
}

// Round 8
// 761.376 us; speedup vs baseline: 4.4909x; 1.1251x over previous
//
#include <hip/hip_runtime.h>
#include <math.h>

#define TB 256
#define SCAN_TOT 106250
#define SCAN_NB  104

typedef __bf16 bf16x8 __attribute__((ext_vector_type(8)));
typedef float f32x4 __attribute__((ext_vector_type(4)));

static __device__ __forceinline__ int gtid() { return blockIdx.x * blockDim.x + threadIdx.x; }

static __device__ __forceinline__ void fma4(float4& a, float s, const float4 b) {
  a.x = fmaf(s, b.x, a.x); a.y = fmaf(s, b.y, a.y);
  a.z = fmaf(s, b.z, a.z); a.w = fmaf(s, b.w, a.w);
}

static __device__ __forceinline__ float bf_lo(unsigned u) {
  union { unsigned u; float f; } c; c.u = u << 16; return c.f;
}
static __device__ __forceinline__ float bf_hi(unsigned u) {
  union { unsigned u; float f; } c; c.u = u & 0xffff0000u; return c.f;
}
static __device__ __forceinline__ float bfus(unsigned short u) {
  union { unsigned u; float f; } c; c.u = ((unsigned)u) << 16; return c.f;
}
static __device__ __forceinline__ unsigned f2bf(float f) {
  union { float f; unsigned u; } c; c.f = f;
  return (c.u + 0x7fffu + ((c.u >> 16) & 1u)) >> 16;
}
static __device__ __forceinline__ unsigned pk2(float a, float b) {
  return f2bf(a) | (f2bf(b) << 16);
}

__global__ void fill_kernel(float* __restrict__ p, int n, float v) {
  int i = gtid(); if (i < n) p[i] = v;
}

__global__ void zero_int_kernel(int* __restrict__ p, int n) {
  int i = gtid(); if (i < n) p[i] = 0;
}

struct SegD {
  const int* rows[8];
  const int* cols[8];
  const float* vals[8];  // null => edge seg (compute sym-norm weight)
  int start[8];
  int degb[8];
};

__global__ void count_all_kernel(SegD sg, int total, int* __restrict__ deg) {
  int t = gtid(); if (t >= total) return;
  int seg = 0;
  #pragma unroll
  for (int q = 1; q < 8; ++q) seg += (t >= sg.start[q]);
  int i = t - sg.start[seg];
  atomicAdd(&deg[sg.degb[seg] + sg.rows[seg][i]], 1);
}

__global__ void fill_all_kernel(SegD sg, int total, const int* __restrict__ deg,
                                const int* __restrict__ offs, int* __restrict__ cursor,
                                int* __restrict__ ccol, float* __restrict__ cwa) {
  int t = gtid(); if (t >= total) return;
  int seg = 0;
  #pragma unroll
  for (int q = 1; q < 8; ++q) seg += (t >= sg.start[q]);
  int i = t - sg.start[seg];
  int db = sg.degb[seg];
  int r = sg.rows[seg][i];
  int c = sg.cols[seg][i];
  int p = atomicAdd(&cursor[db + r], 1);
  int idx = offs[db + r] + p;
  float w;
  if (sg.vals[seg]) {
    w = sg.vals[seg][i];
  } else {
    int dc = deg[db + c];
    w = rsqrtf((float)deg[db + r]) * (dc > 0 ? rsqrtf((float)dc) : 0.f);
  }
  ccol[idx] = c;
  cwa[idx] = w;
}

// ---- 3-phase global exclusive scan over deg ----
__global__ void scan_phase1(const int* __restrict__ in, int* __restrict__ bsum) {
  __shared__ int wsum[4];
  int blk = blockIdx.x, t = threadIdx.x;
  int base = blk * 1024 + t * 4;
  int s = 0;
  #pragma unroll
  for (int q = 0; q < 4; ++q) { int i = base + q; if (i < SCAN_TOT) s += in[i]; }
  #pragma unroll
  for (int o = 32; o > 0; o >>= 1) s += __shfl_xor(s, o, 64);
  int lane = t & 63, wid = t >> 6;
  if (lane == 0) wsum[wid] = s;
  __syncthreads();
  if (t == 0) bsum[blk] = wsum[0] + wsum[1] + wsum[2] + wsum[3];
}

__global__ void scan_phase2(int* __restrict__ bsum, int* __restrict__ offs_end) {
  int t = threadIdx.x;  // 128
  int v = (t < SCAN_NB) ? bsum[t] : 0;
  int lane = t & 63, wid = t >> 6;
  int p = v;
  #pragma unroll
  for (int o = 1; o < 64; o <<= 1) { int u = __shfl_up(p, o, 64); if (lane >= o) p += u; }
  __shared__ int w0tot;
  if (wid == 0 && lane == 63) w0tot = p;
  __syncthreads();
  int incl = p + (wid ? w0tot : 0);
  if (t < SCAN_NB) bsum[t] = incl - v;
  if (t == 127) offs_end[0] = incl;
}

__global__ void scan_phase3(const int* __restrict__ in, const int* __restrict__ bbase,
                            int* __restrict__ offs, int* __restrict__ cursor) {
  __shared__ int wsum[4];
  int blk = blockIdx.x, t = threadIdx.x;
  int base = blk * 1024 + t * 4;
  int v[4]; int s = 0;
  #pragma unroll
  for (int q = 0; q < 4; ++q) { int i = base + q; v[q] = (i < SCAN_TOT) ? in[i] : 0; s += v[q]; }
  int lane = t & 63, wid = t >> 6;
  int p = s;
  #pragma unroll
  for (int o = 1; o < 64; o <<= 1) { int u = __shfl_up(p, o, 64); if (lane >= o) p += u; }
  if (lane == 63) wsum[wid] = p;
  __syncthreads();
  int woff = 0;
  #pragma unroll
  for (int q = 0; q < 4; ++q) woff += (q < wid) ? wsum[q] : 0;
  int ex = bbase[blk] + woff + p - s;
  #pragma unroll
  for (int q = 0; q < 4; ++q) {
    int i = base + q;
    if (i < SCAN_TOT) { offs[i] = ex; cursor[i] = 0; ex += v[q]; }
  }
}

// ---- fp32 pool (upper levels) ----
__global__ void pool_kernel(const float4* __restrict__ x, const int* __restrict__ offs,
                            const int* __restrict__ ccol, const float* __restrict__ cw,
                            float4* __restrict__ out, int n, int xs4, int xoff4,
                            int os4, int osh) {
  int t = gtid();
  if (t >= n * os4) return;
  int v = t >> osh, j = t & (os4 - 1);
  int s = offs[v], e = offs[v + 1];
  float4 a = {0.f, 0.f, 0.f, 0.f};
  for (int i = s; i < e; ++i)
    fma4(a, cw[i], x[(long long)ccol[i] * xs4 + xoff4 + j]);
  out[t] = a;
}

// ---- pool: fp32 [u][16][32] source -> linear bf16 [v][16][32] ----
__global__ void pool_f2b_kernel(const float4* __restrict__ x, const int* __restrict__ offs,
                                const int* __restrict__ ccol, const float* __restrict__ cw,
                                uint4* __restrict__ out, int n) {
  int t = gtid();
  if (t >= n * 64) return;
  int v = t >> 6, j = t & 63;
  int s = offs[v], e = offs[v + 1];
  float4 a0 = {0.f, 0.f, 0.f, 0.f}, a1 = {0.f, 0.f, 0.f, 0.f};
  for (int i = s; i < e; ++i) {
    float w = cw[i];
    const float4* xr = x + (long long)ccol[i] * 128 + j * 2;
    fma4(a0, w, xr[0]); fma4(a1, w, xr[1]);
  }
  uint4 r;
  r.x = pk2(a0.x, a0.y); r.y = pk2(a0.z, a0.w);
  r.z = pk2(a1.x, a1.y); r.w = pk2(a1.z, a1.w);
  out[t] = r;
}

// ---- pool: bf16 [u][16][32] source -> linear bf16 [v][16][32] ----
__global__ void pool_b2b_kernel(const uint4* __restrict__ x, const int* __restrict__ offs,
                                const int* __restrict__ ccol, const float* __restrict__ cw,
                                uint4* __restrict__ out, int n) {
  int t = gtid();
  if (t >= n * 64) return;
  int v = t >> 6, j = t & 63;
  int s = offs[v], e = offs[v + 1];
  float a[8];
  #pragma unroll
  for (int q = 0; q < 8; ++q) a[q] = 0.f;
  for (int i = s; i < e; ++i) {
    float w = cw[i];
    uint4 xv = x[(long long)ccol[i] * 64 + j];
    a[0] = fmaf(w, bf_lo(xv.x), a[0]); a[1] = fmaf(w, bf_hi(xv.x), a[1]);
    a[2] = fmaf(w, bf_lo(xv.y), a[2]); a[3] = fmaf(w, bf_hi(xv.y), a[3]);
    a[4] = fmaf(w, bf_lo(xv.z), a[4]); a[5] = fmaf(w, bf_hi(xv.z), a[5]);
    a[6] = fmaf(w, bf_lo(xv.w), a[6]); a[7] = fmaf(w, bf_hi(xv.w), a[7]);
  }
  uint4 r;
  r.x = pk2(a[0], a[1]); r.y = pk2(a[2], a[3]);
  r.z = pk2(a[4], a[5]); r.w = pk2(a[6], a[7]);
  out[t] = r;
}

// ---- fp32 channel-split Clenshaw step (upper levels j=0,1) ----
template<int CIN, int COUT>
__global__ void cheb_step_kernel(const float* __restrict__ X,
                                 const float* __restrict__ b1,
                                 float* __restrict__ b2o,
                                 const float* __restrict__ Wk,
                                 const float* __restrict__ bias,
                                 const int* __restrict__ offs,
                                 const int* __restrict__ ccol,
                                 const float* __restrict__ cw,
                                 int n, int LB, int mode) {
  constexpr int CS = COUT / 8;
  constexpr int LCS = (CS == 8) ? 3 : 2;
  constexpr int W4 = COUT / 4;
  __shared__ float sW[CIN * COUT];
  for (int i = threadIdx.x; i < CIN * COUT; i += blockDim.x) sW[i] = Wk[i];
  __syncthreads();
  int t = gtid();
  int BI = 1 << LB;
  if (t >= n * BI * CS) return;
  int cs = t & (CS - 1);
  int r = t >> LCS;
  int v = r >> LB;
  int bi = r & (BI - 1);
  float4 a0 = {0.f, 0.f, 0.f, 0.f}, a1 = {0.f, 0.f, 0.f, 0.f};
  const float4* Xr = (const float4*)(X + (long long)r * CIN);
  const float4* wbase = ((const float4*)sW) + cs * 2;
  #pragma unroll
  for (int c4 = 0; c4 < CIN / 4; ++c4) {
    float4 xv = Xr[c4];
    const float4* w = wbase + (c4 * 4) * W4;
    fma4(a0, xv.x, w[0]); fma4(a1, xv.x, w[1]); w += W4;
    fma4(a0, xv.y, w[0]); fma4(a1, xv.y, w[1]); w += W4;
    fma4(a0, xv.z, w[0]); fma4(a1, xv.z, w[1]); w += W4;
    fma4(a0, xv.w, w[0]); fma4(a1, xv.w, w[1]);
  }
  if (mode >= 1) {
    float sc = (mode == 3) ? 1.f : 2.f;
    int s = offs[v], e = offs[v + 1];
    const float4* b14 = (const float4*)b1;
    for (int i = s; i < e; ++i) {
      float w = cw[i] * sc;
      long long rb = (long long)((ccol[i] << LB) | bi) * W4 + cs * 2;
      fma4(a0, w, b14[rb]); fma4(a1, w, b14[rb + 1]);
    }
  }
  float4* Or = ((float4*)b2o) + (long long)r * W4 + cs * 2;
  if (mode >= 2) {
    float4 p0 = Or[0], p1 = Or[1];
    a0.x -= p0.x; a0.y -= p0.y; a0.z -= p0.z; a0.w -= p0.w;
    a1.x -= p1.x; a1.y -= p1.y; a1.z -= p1.z; a1.w -= p1.w;
  }
  if (mode == 3) {
    const float* bs = bias + cs * 8;
    a0.x += bs[0]; a0.y += bs[1]; a0.z += bs[2]; a0.w += bs[3];
    a1.x += bs[4]; a1.y += bs[5]; a1.z += bs[6]; a1.w += bs[7];
    a0.x = a0.x > 0.f ? a0.x : expm1f(a0.x);
    a0.y = a0.y > 0.f ? a0.y : expm1f(a0.y);
    a0.z = a0.z > 0.f ? a0.z : expm1f(a0.z);
    a0.w = a0.w > 0.f ? a0.w : expm1f(a0.w);
    a1.x = a1.x > 0.f ? a1.x : expm1f(a1.x);
    a1.y = a1.y > 0.f ? a1.y : expm1f(a1.y);
    a1.z = a1.z > 0.f ? a1.z : expm1f(a1.z);
    a1.w = a1.w > 0.f ? a1.w : expm1f(a1.w);
  }
  Or[0] = a0; Or[1] = a1;
}

// ---- MFMA Clenshaw step (CIN=COUT=32, BI=16): one wave per vertex ----
// X: linear bf16 [n*16][32] (A-frag = one uint4/lane).
// State b1/b2o: PAIR-INTERLEAVED bf16 — 16 uints/row, uint p = (col p, col p+16).
// mode<3 writes interleaved; mode 3 writes LINEAR bf16 (ok in-place: the owning
// wave's loads complete before its stores; no other wave touches vertex v).
__global__ void __launch_bounds__(256)
cheb_mfma32_kernel(const uint4* __restrict__ X,
                   const unsigned* __restrict__ b1,
                   unsigned* __restrict__ b2o,
                   const float* __restrict__ Wk,
                   const float* __restrict__ bias,
                   const int* __restrict__ offs,
                   const int* __restrict__ ccol,
                   const float* __restrict__ cw,
                   int n, int mode) {
  int lane = threadIdx.x & 63;
  int v = (blockIdx.x << 2) | (threadIdx.x >> 6);
  if (v >= n) return;
  int g = lane >> 4;
  int c15 = lane & 15;

  union { uint4 u; bf16x8 v; } Au;
  Au.u = X[((long long)(v * 16 + c15)) * 4 + g];

  bf16x8 B0, B1;
  #pragma unroll
  for (int j = 0; j < 8; ++j) {
    int k = 8 * g + j;
    B0[j] = (__bf16)Wk[k * 32 + c15];
    B1[j] = (__bf16)Wk[k * 32 + 16 + c15];
  }
  f32x4 z = {0.f, 0.f, 0.f, 0.f};
  f32x4 acc0 = __builtin_amdgcn_mfma_f32_16x16x32_bf16(Au.v, B0, z, 0, 0, 0);
  f32x4 acc1 = __builtin_amdgcn_mfma_f32_16x16x32_bf16(Au.v, B1, z, 0, 0, 0);

  if (mode >= 1) {
    float sc = (mode == 3) ? 1.f : 2.f;
    int s = offs[v], e = offs[v + 1];
    for (int i = s; i < e; ++i) {
      float w = cw[i] * sc;
      long long base = (long long)ccol[i] * 256 + 64 * g + c15;
      #pragma unroll
      for (int q = 0; q < 4; ++q) {
        unsigned pv = b1[base + 16 * q];
        acc0[q] = fmaf(w, bf_lo(pv), acc0[q]);
        acc1[q] = fmaf(w, bf_hi(pv), acc1[q]);
      }
    }
  }
  long long rb = (long long)v * 256 + 64 * g + c15;
  if (mode >= 2) {
    #pragma unroll
    for (int q = 0; q < 4; ++q) {
      unsigned pv = b2o[rb + 16 * q];
      acc0[q] -= bf_lo(pv);
      acc1[q] -= bf_hi(pv);
    }
  }
  if (mode == 3) {
    float bs0 = bias[c15], bs1 = bias[16 + c15];
    unsigned short* o = (unsigned short*)b2o;
    long long lb = ((long long)v * 16 + 4 * g) * 32;
    #pragma unroll
    for (int q = 0; q < 4; ++q) {
      float a = acc0[q] + bs0;
      float b = acc1[q] + bs1;
      a = a > 0.f ? a : expm1f(a);
      b = b > 0.f ? b : expm1f(b);
      o[lb + q * 32 + c15] = (unsigned short)f2bf(a);
      o[lb + q * 32 + 16 + c15] = (unsigned short)f2bf(b);
    }
  } else {
    #pragma unroll
    for (int q = 0; q < 4; ++q)
      b2o[rb + 16 * q] = pk2(acc0[q], acc1[q]);
  }
}

// c_all[k][r][3] (bf16) = X[r]·Wout[k], X linear bf16 [r][32], r over n*16
__global__ void gemm_out_all_kernel(const uint4* __restrict__ X, const float* __restrict__ W,
                                    unsigned short* __restrict__ c_all, int nr) {
  __shared__ float sW[576];
  for (int i = threadIdx.x; i < 576; i += blockDim.x) sW[i] = W[i];
  __syncthreads();
  int r = gtid();
  if (r >= nr) return;
  const uint4* Xr = X + (long long)r * 4;
  float xa[32];
  #pragma unroll
  for (int q = 0; q < 4; ++q) {
    uint4 xv = Xr[q];
    xa[q * 8 + 0] = bf_lo(xv.x); xa[q * 8 + 1] = bf_hi(xv.x);
    xa[q * 8 + 2] = bf_lo(xv.y); xa[q * 8 + 3] = bf_hi(xv.y);
    xa[q * 8 + 4] = bf_lo(xv.z); xa[q * 8 + 5] = bf_hi(xv.z);
    xa[q * 8 + 6] = bf_lo(xv.w); xa[q * 8 + 7] = bf_hi(xv.w);
  }
  float acc[18];
  #pragma unroll
  for (int i = 0; i < 18; ++i) acc[i] = 0.f;
  #pragma unroll
  for (int c = 0; c < 32; ++c) {
    float xc = xa[c];
    #pragma unroll
    for (int k = 0; k < 6; ++k) {
      acc[k * 3 + 0] = fmaf(xc, sW[k * 96 + c * 3 + 0], acc[k * 3 + 0]);
      acc[k * 3 + 1] = fmaf(xc, sW[k * 96 + c * 3 + 1], acc[k * 3 + 1]);
      acc[k * 3 + 2] = fmaf(xc, sW[k * 96 + c * 3 + 2], acc[k * 3 + 2]);
    }
  }
  #pragma unroll
  for (int k = 0; k < 6; ++k) {
    unsigned short* o = c_all + ((long long)k * nr + r) * 3;
    o[0] = (unsigned short)f2bf(acc[k * 3 + 0]);
    o[1] = (unsigned short)f2bf(acc[k * 3 + 1]);
    o[2] = (unsigned short)f2bf(acc[k * 3 + 2]);
  }
}

// Clenshaw on tiny 3-ch buffers, full batch; r = v*16+bi; mode3 -> dout[(bi*n+v)*3]
__global__ void cheb_out_step_kernel(const unsigned short* __restrict__ c_all, int k,
                                     const float* __restrict__ b1,
                                     float* __restrict__ b2o,
                                     const float* __restrict__ bias,
                                     const int* __restrict__ offs,
                                     const int* __restrict__ ccol,
                                     const float* __restrict__ cw,
                                     int n, float* __restrict__ dout, int mode) {
  int r = gtid();
  if (r >= n * 16) return;
  int v = r >> 4, bi = r & 15;
  const unsigned short* cr = c_all + ((long long)k * n * 16 + r) * 3;
  float a0 = bfus(cr[0]), a1 = bfus(cr[1]), a2 = bfus(cr[2]);
  if (mode >= 1) {
    float sc = (mode == 3) ? 1.f : 2.f;
    int s = offs[v], e = offs[v + 1];
    for (int i = s; i < e; ++i) {
      float w = cw[i] * sc;
      const float* br = b1 + (long long)((ccol[i] << 4) | bi) * 3;
      a0 = fmaf(w, br[0], a0); a1 = fmaf(w, br[1], a1); a2 = fmaf(w, br[2], a2);
    }
  }
  if (mode >= 2) {
    const float* p = b2o + (long long)r * 3;
    a0 -= p[0]; a1 -= p[1]; a2 -= p[2];
  }
  if (mode == 3) {
    a0 += bias[0]; a1 += bias[1]; a2 += bias[2];
    float* o = dout + ((long long)bi * n + v) * 3;
    o[0] = a0; o[1] = a1; o[2] = a2;
  } else {
    float* o = b2o + (long long)r * 3;
    o[0] = a0; o[1] = a1; o[2] = a2;
  }
}

__global__ void linear_kernel(const float* __restrict__ x, const float* __restrict__ w,
                              const float* __restrict__ bias, float* __restrict__ out) {
  int t = gtid();
  const int TOT = 157 * 16 * 64;
  if (t >= TOT) return;
  int c = t & 63;
  int b = (t >> 6) & 15;
  int v = t >> 10;
  int colw = v * 64 + c;
  float acc = bias[colw];
  const float* xr = x + b * 128;
  for (int k = 0; k < 128; ++k) acc = fmaf(xr[k], w[k * 10048 + colw], acc);
  out[t] = acc;
}

extern "C" void kernel_launch(void* const* d_in, const int* in_sizes, int n_in,
                              void* d_out, int out_size, void* d_ws, size_t ws_size,
                              hipStream_t stream) {
  const int N[4] = {40000, 10000, 2500, 625};
  const int E[4] = {240000, 60000, 15000, 3750};
  const int NNZ[4] = {120000, 30000, 7500, 1875};
  const int DP[4] = {0, 40000, 50000, 52500};
  const int DE[4] = {53125, 93125, 103125, 105625};
  const int ITEMS = 478125;

  const float* x     = (const float*)d_in[0];
  const float* lin_w = (const float*)d_in[1];
  const float* lin_b = (const float*)d_in[2];
  const int* edge[4] = {(const int*)d_in[3], (const int*)d_in[4], (const int*)d_in[5], (const int*)d_in[6]};
  const int* up_row[4]; const int* up_col[4]; const float* up_val[4];
  for (int i = 0; i < 4; ++i) {
    up_row[i] = (const int*)d_in[7 + 3 * i];
    up_col[i] = (const int*)d_in[8 + 3 * i];
    up_val[i] = (const float*)d_in[9 + 3 * i];
  }
  const float* W_[5] = {(const float*)d_in[19], (const float*)d_in[21], (const float*)d_in[23],
                        (const float*)d_in[25], (const float*)d_in[27]};
  const float* b_[5] = {(const float*)d_in[20], (const float*)d_in[22], (const float*)d_in[24],
                        (const float*)d_in[26], (const float*)d_in[28]};

  char* ws = (char*)d_ws;
  size_t off = 0;
  auto alloc = [&](size_t bytes) -> void* {
    void* p = ws + off;
    off = (off + bytes + 255) & ~(size_t)255;
    return p;
  };
  auto cdiv = [](int a, int b) { return (a + b - 1) / b; };

  float* slot[4];
  for (int i = 0; i < 4; ++i) slot[i] = (float*)alloc(20480000ull);  // fp32 / level-1 bf16
  uint4* Ab = (uint4*)alloc(40960000ull);  // level-0 bf16 X (linear)
  unsigned* Bb = (unsigned*)alloc(40960000ull);  // level-0 state (interleaved)
  unsigned* Cb = (unsigned*)alloc(40960000ull);  // level-0 state / h0 linear
  unsigned short* c_all = (unsigned short*)alloc((size_t)6 * 640000 * 3 * 2);  // 23 MB
  float* ob1 = (float*)alloc((size_t)640000 * 3 * 4);
  float* ob2 = (float*)alloc((size_t)640000 * 3 * 4);
  int* deg_all    = (int*)alloc(SCAN_TOT * 4);
  int* cursor_all = (int*)alloc(SCAN_TOT * 4);
  int* offs_all   = (int*)alloc((SCAN_TOT + 1) * 4);
  int* bsum       = (int*)alloc(SCAN_NB * 4);
  int* col_arena  = (int*)alloc((size_t)ITEMS * 4);
  float* w_arena  = (float*)alloc((size_t)ITEMS * 4);

  if (off > ws_size) {
    fill_kernel<<<cdiv(out_size, TB), TB, 0, stream>>>((float*)d_out, out_size,
                                                       (float)(ws_size >> 20));
    return;
  }

  // ---- batched CSR build ----
  SegD sg;
  int cum = 0;
  for (int l = 0; l < 4; ++l) {
    sg.rows[l] = up_row[l]; sg.cols[l] = up_col[l]; sg.vals[l] = up_val[l];
    sg.start[l] = cum; sg.degb[l] = DP[l]; cum += NNZ[l];
  }
  for (int l = 0; l < 4; ++l) {
    sg.rows[4 + l] = edge[l]; sg.cols[4 + l] = edge[l] + E[l]; sg.vals[4 + l] = nullptr;
    sg.start[4 + l] = cum; sg.degb[4 + l] = DE[l]; cum += E[l];
  }
  zero_int_kernel<<<cdiv(SCAN_TOT, TB), TB, 0, stream>>>(deg_all, SCAN_TOT);
  count_all_kernel<<<cdiv(ITEMS, TB), TB, 0, stream>>>(sg, ITEMS, deg_all);
  scan_phase1<<<SCAN_NB, TB, 0, stream>>>(deg_all, bsum);
  scan_phase2<<<1, 128, 0, stream>>>(bsum, offs_all + SCAN_TOT);
  scan_phase3<<<SCAN_NB, TB, 0, stream>>>(deg_all, bsum, offs_all, cursor_all);
  fill_all_kernel<<<cdiv(ITEMS, TB), TB, 0, stream>>>(sg, ITEMS, deg_all, offs_all,
                                                      cursor_all, col_arena, w_arena);

  // latent -> h4 [157][16][64]
  linear_kernel<<<cdiv(157 * 16 * 64, TB), TB, 0, stream>>>(x, lin_w, lin_b, slot[0]);
  float* H = slot[0];
  float* A = slot[1];
  float* B = slot[2];
  float* C = slot[3];

  const int CINA[2]  = {64, 64};
  const int COUTA[2] = {64, 32};

  // ---- deblocks j=0,1 on meshes 3,2 (fp32, BI=16) ----
  for (int j = 0; j < 2; ++j) {
    int lvl = 3 - j;
    int n = N[lvl];
    int cin = CINA[j], cout = COUTA[j];
    int os4 = 16 * cin / 4;
    int osh = (os4 == 256) ? 8 : 7;
    const int* offs_p = offs_all + DP[lvl];
    const int* offs_e = offs_all + DE[lvl];

    pool_kernel<<<cdiv(n * os4, TB), TB, 0, stream>>>(
        (const float4*)H, offs_p, col_arena, w_arena, (float4*)A, n, os4, 0, os4, osh);

    int cs = cout / 8;
    dim3 g(cdiv(n * 16 * cs, TB));
    auto step = [&](const float* b1, float* b2o, int k, int mode) {
      const float* Wk = W_[j] + (size_t)k * cin * cout;
      if (cin == 64 && cout == 64)
        hipLaunchKernelGGL((cheb_step_kernel<64, 64>), g, dim3(TB), 0, stream,
                           A, b1, b2o, Wk, b_[j], offs_e, col_arena, w_arena, n, 4, mode);
      else
        hipLaunchKernelGGL((cheb_step_kernel<64, 32>), g, dim3(TB), 0, stream,
                           A, b1, b2o, Wk, b_[j], offs_e, col_arena, w_arena, n, 4, mode);
    };
    step(nullptr, B, 5, 0);
    step(B, C, 4, 1);
    step(C, B, 3, 2);
    step(B, C, 2, 2);
    step(C, B, 1, 2);
    step(B, C, 0, 3);

    float* tmp = H; H = C; C = tmp;
  }
  // After j=0,1: H holds h2 fp32 [2500][16][32]; slot[1],slot[2],slot[3]-region free
  // (H is one of slot0/slot3; A=slot1 free; the two non-H of {slot0,slot2,slot3} free.)
  float* freeA = A;                      // slot[1]
  float* freeB = B;                      // slot[2]
  float* freeC = C;                      // whichever of slot0/slot3 H isn't

  // ---- deblock j=2 on mesh 1 via MFMA (bf16) ----
  uint4* Ab1 = (uint4*)freeA;
  unsigned* Bb1 = (unsigned*)freeB;
  unsigned* Cb1 = (unsigned*)freeC;
  {
    int n = N[1];  // 10000
    const int* offs_p = offs_all + DP[1];
    const int* offs_e = offs_all + DE[1];
    pool_f2b_kernel<<<cdiv(n * 64, TB), TB, 0, stream>>>(
        (const float4*)H, offs_p, col_arena, w_arena, Ab1, n);
    dim3 gmf(n / 4);
    auto dstep = [&](const unsigned* b1, unsigned* b2o, int k, int mode) {
      cheb_mfma32_kernel<<<gmf, dim3(TB), 0, stream>>>(
          Ab1, b1, b2o, W_[2] + (size_t)k * 1024, b_[2],
          offs_e, col_arena, w_arena, n, mode);
    };
    dstep(nullptr, Bb1, 5, 0);
    dstep(Bb1, Cb1, 4, 1);
    dstep(Cb1, Bb1, 3, 2);
    dstep(Bb1, Cb1, 2, 2);
    dstep(Cb1, Bb1, 1, 2);
    dstep(Bb1, Cb1, 0, 3);   // h1 linear bf16 in Cb1
  }

  // ---- level 0: deblock j=3 via MFMA + out conv ----
  {
    int n = N[0];
    int nr = n * 16;
    const int* offs_p = offs_all + DP[0];
    const int* offs_e = offs_all + DE[0];

    pool_b2b_kernel<<<cdiv(n * 64, TB), TB, 0, stream>>>(
        (const uint4*)Cb1, offs_p, col_arena, w_arena, Ab, n);

    dim3 gmf(n / 4);
    auto dstep = [&](const unsigned* b1, unsigned* b2o, int k, int mode) {
      cheb_mfma32_kernel<<<gmf, dim3(TB), 0, stream>>>(
          Ab, b1, b2o, W_[3] + (size_t)k * 1024, b_[3],
          offs_e, col_arena, w_arena, n, mode);
    };
    dstep(nullptr, Bb, 5, 0);
    dstep(Bb, Cb, 4, 1);
    dstep(Cb, Bb, 3, 2);
    dstep(Bb, Cb, 2, 2);
    dstep(Cb, Bb, 1, 2);
    dstep(Bb, Cb, 0, 3);   // h0 linear bf16 in Cb

    dim3 gr(cdiv(nr, TB));
    gemm_out_all_kernel<<<gr, dim3(TB), 0, stream>>>((const uint4*)Cb, W_[4], c_all, nr);
    float* dout = (float*)d_out;
    auto ostep = [&](const float* b1, float* b2o, int k, int mode) {
      cheb_out_step_kernel<<<gr, dim3(TB), 0, stream>>>(
          c_all, k, b1, b2o, b_[4], offs_e, col_arena, w_arena, n, dout, mode);
    };
    ostep(nullptr, ob1, 5, 0);
    ostep(ob1, ob2, 4, 1);
    ostep(ob2, ob1, 3, 2);
    ostep(ob1, ob2, 2, 2);
    ostep(ob2, ob1, 1, 2);
    ostep(ob1, ob2, 0, 3);
  }
}